// Round 4
// baseline (8851.729 us; speedup 1.0000x reference)
//
#include <hip/hip_runtime.h>
#include <math.h>

// ---------------------------------------------------------------------------
// LphaLoss: blockwise VGG19(conv3_1) FFT-phase cosine mask + masked L1.
// fp32 everywhere (mask threshold sim>=0.2 is a discontinuity).
//
// ws layout (floats), chunked over T tasks (T adaptive to ws_size):
//   pool1 : [T][64][16][16]  = T*16384   (reused as phase buffer by k3)
//   pool2 : [2][T][128][8][8]= T*16384
//   w5t   : [128*9][256]     = 294912    (transposed conv3 weights)
//   mask  : [1024], accum : [1]
// footprint = (T*32768 + 294912 + 2048) * 4 bytes.
// ---------------------------------------------------------------------------

typedef float f8 __attribute__((ext_vector_type(8)));

__device__ __forceinline__ f8 sp8(float w) { return (f8){w, w, w, w, w, w, w, w}; }

__device__ __forceinline__ float wave_reduce_sum(float v) {
#pragma unroll
  for (int off = 32; off > 0; off >>= 1) v += __shfl_down(v, off);
  return v;
}

__global__ void k0_zero(float* acc) { acc[0] = 0.f; }

// transpose w5 [256co][128ci][9] -> w5t [128ci*9][256co]
__global__ __launch_bounds__(256) void k_w5t(const float* __restrict__ w5,
                                             float* __restrict__ w5t) {
  const int e = blockIdx.x * 256 + threadIdx.x;   // grid 1152*256 = 294912
  const int co = e & 255, t = e >> 8;
  w5t[t * 256 + co] = w5[co * 1152 + t];
}

// ---------------- K1: conv1_1+relu -> conv1_2+relu -> pool1 ----------------
__global__ __launch_bounds__(512) void k1_conv1(const float* __restrict__ src,
                                                const float* __restrict__ w1,
                                                const float* __restrict__ b1,
                                                const float* __restrict__ w2,
                                                const float* __restrict__ b2,
                                                float* __restrict__ pool1,
                                                int task_base) {
  const int btl = blockIdx.x;
  const int bt = btl + task_base;
  const int img = bt >> 6, by = (bt >> 3) & 7, bx = bt & 7;
  const int tid = threadIdx.x;

  __shared__ float lin[3 * 34 * 34];
  __shared__ float w1s[64 * 27];
  __shared__ float b1s[64], b2s[64];
  __shared__ float c11[64 * 10 * 34];

  for (int idx = tid; idx < 3 * 34 * 34; idx += 512) {
    int c = idx / 1156;
    int rm = idx - c * 1156;
    int row = rm / 34;
    int xx = rm - row * 34 - 1;
    int yy = row - 1;
    float v = 0.f;
    if (yy >= 0 && yy < 32 && xx >= 0 && xx < 32) {
      float m = (c == 0) ? 0.485f : (c == 1) ? 0.456f : 0.406f;
      float sd = (c == 0) ? 0.229f : (c == 1) ? 0.224f : 0.225f;
      v = (src[((img * 3 + c) * 256 + (by * 32 + yy)) * 256 + (bx * 32 + xx)] - m) / sd;
    }
    lin[idx] = v;
  }
  for (int idx = tid; idx < 64 * 27; idx += 512) w1s[idx] = w1[idx];
  if (tid < 64) b1s[tid] = b1[tid];
  else if (tid < 128) b2s[tid - 64] = b2[tid - 64];

  const int cogs = __builtin_amdgcn_readfirstlane(tid >> 6);  // wave id
  const int lane = tid & 63;
  const int col = lane & 31;    // conv col 0..31 (stride-1 across lanes)
  const int rg = lane >> 5;     // row group 0..1; rows {rg, rg+2, rg+4, rg+6}

  __syncthreads();

  for (int q = 0; q < 4; ++q) {
    const int y0 = q * 8;
    if (q) __syncthreads();
    // conv1_1 + relu into c11 (rows y0-1 .. y0+8, col-halo padded)
    for (int e = tid; e < 64 * 10 * 34; e += 512) {
      int ch = e / 340;
      int rm = e - ch * 340;
      int r = rm / 34;
      int xp = rm - r * 34;
      int y = y0 - 1 + r;
      int x = xp - 1;
      float v = 0.f;
      if (y >= 0 && y < 32 && x >= 0 && x < 32) {
        float a = b1s[ch];
        const float* wp = &w1s[ch * 27];
#pragma unroll
        for (int ci = 0; ci < 3; ++ci) {
          const float* lp = &lin[ci * 1156 + y * 34 + x];
#pragma unroll
          for (int ky = 0; ky < 3; ++ky)
#pragma unroll
            for (int kx = 0; kx < 3; ++kx)
              a = fmaf(lp[ky * 34 + kx], wp[ci * 9 + ky * 3 + kx], a);
        }
        v = fmaxf(a, 0.f);
      }
      c11[e] = v;
    }
    __syncthreads();

    // conv1_2 (+bias+relu) + 2x2 pool, stride-1 lane mapping (no 4-way LDS conflict)
    float acc[8][4];
#pragma unroll
    for (int a = 0; a < 8; ++a)
#pragma unroll
      for (int rr = 0; rr < 4; ++rr) acc[a][rr] = 0.f;

    const float* w2g = w2 + cogs * 8 * 576;
    for (int ci = 0; ci < 64; ++ci) {
      const float* c1b = &c11[ci * 340];
#pragma unroll
      for (int ky = 0; ky < 3; ++ky) {
#pragma unroll
        for (int kx = 0; kx < 3; ++kx) {
          const float* w2c = w2g + ci * 9 + ky * 3 + kx;
          float wv[8];
#pragma unroll
          for (int a = 0; a < 8; ++a) wv[a] = w2c[a * 576];
          const float in0 = c1b[(rg + 0 + ky) * 34 + col + kx];
          const float in1 = c1b[(rg + 2 + ky) * 34 + col + kx];
          const float in2 = c1b[(rg + 4 + ky) * 34 + col + kx];
          const float in3 = c1b[(rg + 6 + ky) * 34 + col + kx];
#pragma unroll
          for (int a = 0; a < 8; ++a) {
            acc[a][0] = fmaf(in0, wv[a], acc[a][0]);
            acc[a][1] = fmaf(in1, wv[a], acc[a][1]);
            acc[a][2] = fmaf(in2, wv[a], acc[a][2]);
            acc[a][3] = fmaf(in3, wv[a], acc[a][3]);
          }
        }
      }
    }
#pragma unroll
    for (int a = 0; a < 8; ++a) {
      const int co = cogs * 8 + a;
      const float bb = b2s[co];
#pragma unroll
      for (int rr = 0; rr < 4; ++rr) {
        float v = fmaxf(acc[a][rr] + bb, 0.f);
        v = fmaxf(v, __shfl_xor(v, 1));    // pool cols (2c, 2c+1)
        v = fmaxf(v, __shfl_xor(v, 32));   // pool rows (2r, 2r+1)
        if (rg == 0 && !(col & 1))
          pool1[((btl * 64 + co) * 16 + q * 4 + rr) * 16 + (col >> 1)] = v;
      }
    }
  }
}

// ---------------- K2: conv2_1+relu -> conv2_2+relu -> pool2 ----------------
__global__ __launch_bounds__(512) void k2_conv2(const float* __restrict__ pool1,
                                                const float* __restrict__ w3,
                                                const float* __restrict__ b3,
                                                const float* __restrict__ w4,
                                                const float* __restrict__ b4,
                                                float* __restrict__ pool2) {
  const int bt = blockIdx.x;
  const int tid = threadIdx.x;
  __shared__ float lin2[64 * 256];
  __shared__ float c21[128 * 10 * 18];
  __shared__ float b3s[128], b4s[128];

  for (int idx = tid; idx < 64 * 256; idx += 512) lin2[idx] = pool1[bt * 16384 + idx];
  if (tid < 128) b3s[tid] = b3[tid];
  else if (tid < 256) b4s[tid - 128] = b4[tid - 128];

  const int wv_id = __builtin_amdgcn_readfirstlane(tid >> 6);
  const int lane = tid & 63;

  __syncthreads();

  for (int h = 0; h < 2; ++h) {
    const int y0 = h * 8;
    if (h) __syncthreads();
    // ---- conv2_1 (+bias+relu) into c21 rows y0-1..y0+8 ----
    {
      const int rq = lane >> 4;
      const int xc = lane & 15;
#pragma unroll
      for (int p = 0; p < 2; ++p) {
        const int cg = wv_id * 2 + p;
        const float* w3g = w3 + cg * 8 * 576;
        float a21[8][3];
#pragma unroll
        for (int a = 0; a < 8; ++a)
#pragma unroll
          for (int rr = 0; rr < 3; ++rr) a21[a][rr] = 0.f;
        for (int ci = 0; ci < 64; ++ci) {
          const float* l2 = &lin2[ci * 256];
          const float* w3c = w3g + ci * 9;
#pragma unroll
          for (int ky = 0; ky < 3; ++ky) {
#pragma unroll
            for (int kx = 0; kx < 3; ++kx) {
              float wv[8];
#pragma unroll
              for (int a = 0; a < 8; ++a) wv[a] = w3c[a * 576 + ky * 3 + kx];
              const int xin = xc + kx - 1;
              const bool xok = (xin >= 0) && (xin < 16);
#pragma unroll
              for (int rr = 0; rr < 3; ++rr) {
                const int r = rq + rr * 4;
                const int yin = y0 - 2 + r + ky;
                float inv = 0.f;
                if (xok && r < 10 && yin >= 0 && yin < 16) inv = l2[yin * 16 + xin];
#pragma unroll
                for (int a = 0; a < 8; ++a) a21[a][rr] = fmaf(inv, wv[a], a21[a][rr]);
              }
            }
          }
        }
#pragma unroll
        for (int a = 0; a < 8; ++a) {
          const int ch = cg * 8 + a;
          const float bb = b3s[ch];
#pragma unroll
          for (int rr = 0; rr < 3; ++rr) {
            const int r = rq + rr * 4;
            if (r < 10) {
              const int y = y0 - 1 + r;
              float v = (y >= 0 && y < 16) ? fmaxf(a21[a][rr] + bb, 0.f) : 0.f;
              c21[(ch * 10 + r) * 18 + xc + 1] = v;
              if (xc == 0) c21[(ch * 10 + r) * 18 + 0] = 0.f;
              if (xc == 15) c21[(ch * 10 + r) * 18 + 17] = 0.f;
            }
          }
        }
      }
    }
    __syncthreads();
    // ---- conv2_2 (+bias+relu) + 2x2 pool, stride-1 lane mapping ----
    {
      const int col2 = lane & 15;   // conv col 0..15
      const int rg2 = lane >> 4;    // 0..3; rows {rg2, rg2+4}
#pragma unroll
      for (int p = 0; p < 2; ++p) {
        const int cg = wv_id * 2 + p;
        const float* w4g = w4 + cg * 8 * 1152;
        float a22[8][2];
#pragma unroll
        for (int a = 0; a < 8; ++a) { a22[a][0] = 0.f; a22[a][1] = 0.f; }
        for (int ci = 0; ci < 128; ++ci) {
          const float* c2b = &c21[ci * 180];
#pragma unroll
          for (int ky = 0; ky < 3; ++ky) {
#pragma unroll
            for (int kx = 0; kx < 3; ++kx) {
              const float* w4c = w4g + ci * 9 + ky * 3 + kx;
              float wv[8];
#pragma unroll
              for (int a = 0; a < 8; ++a) wv[a] = w4c[a * 1152];
              const float i0 = c2b[(rg2 + 0 + ky) * 18 + col2 + kx];
              const float i1 = c2b[(rg2 + 4 + ky) * 18 + col2 + kx];
#pragma unroll
              for (int a = 0; a < 8; ++a) {
                a22[a][0] = fmaf(i0, wv[a], a22[a][0]);
                a22[a][1] = fmaf(i1, wv[a], a22[a][1]);
              }
            }
          }
        }
#pragma unroll
        for (int a = 0; a < 8; ++a) {
          const int ch = cg * 8 + a;
          const float bb = b4s[ch];
#pragma unroll
          for (int j = 0; j < 2; ++j) {
            float v = fmaxf(a22[a][j] + bb, 0.f);
            v = fmaxf(v, __shfl_xor(v, 1));    // pool cols
            v = fmaxf(v, __shfl_xor(v, 16));   // pool rows (rg pairs 0-1, 2-3)
            if (!(rg2 & 1) && !(col2 & 1)) {
              const int prow = h * 4 + j * 2 + (rg2 >> 1);
              pool2[(bt * 128 + ch) * 64 + prow * 8 + (col2 >> 1)] = v;
            }
          }
        }
      }
    }
  }
}

// -------- K3: conv3_1 (both streams) + FFT2 phase + cosine sim -> mask -----
// All per-thread state in NAMED registers (no indexable arrays -> no scratch).
#define C707 0.70710678118654752f

// forward complex FFT8 (matches jnp.fft convention, exp(-i...))
#define FFT8(R0,R1,R2,R3,R4,R5,R6,R7,I0,I1,I2,I3,I4,I5,I6,I7) {              \
  float er0=R0+R4, er1=R0-R4, ei0=I0+I4, ei1=I0-I4;                          \
  float er2=R2+R6, er3=R2-R6, ei2=I2+I6, ei3=I2-I6;                          \
  float E0r=er0+er2, E0i=ei0+ei2, E2r=er0-er2, E2i=ei0-ei2;                  \
  float E1r=er1+ei3, E1i=ei1-er3, E3r=er1-ei3, E3i=ei1+er3;                  \
  float or0=R1+R5, or1=R1-R5, oi0=I1+I5, oi1=I1-I5;                          \
  float or2=R3+R7, or3=R3-R7, oi2=I3+I7, oi3=I3-I7;                          \
  float O0r=or0+or2, O0i=oi0+oi2, O2r=or0-or2, O2i=oi0-oi2;                  \
  float O1r=or1+oi3, O1i=oi1-or3, O3r=or1-oi3, O3i=oi1+or3;                  \
  float T1r=C707*(O1r+O1i), T1i=C707*(O1i-O1r);                              \
  float T2r=O2i, T2i=-O2r;                                                   \
  float T3r=C707*(O3i-O3r), T3i=-C707*(O3r+O3i);                             \
  R0=E0r+O0r; I0=E0i+O0i; R4=E0r-O0r; I4=E0i-O0i;                            \
  R1=E1r+T1r; I1=E1i+T1i; R5=E1r-T1r; I5=E1i-T1i;                            \
  R2=E2r+T2r; I2=E2i+T2i; R6=E2r-T2r; I6=E2i-T2i;                            \
  R3=E3r+T3r; I3=E3i+T3i; R7=E3r-T3r; I7=E3i-T3i;                            \
}

// input row IR contributes to out rows IR+1 (ky=0), IR (ky=1), IR-1 (ky=2)
#define CONVROW(IR, AP, AC, AN) {                                            \
  const float4 lo = *(const float4*)(lc + (IR) * 8);                         \
  const float4 hi = *(const float4*)(lc + (IR) * 8 + 4);                     \
  f8 vm = {0.f, lo.x, lo.y, lo.z, lo.w, hi.x, hi.y, hi.z};                   \
  f8 vc = {lo.x, lo.y, lo.z, lo.w, hi.x, hi.y, hi.z, hi.w};                  \
  f8 vp = {lo.y, lo.z, lo.w, hi.x, hi.y, hi.z, hi.w, 0.f};                   \
  AN = __builtin_elementwise_fma(vm, sp8(wv0), AN);                          \
  AN = __builtin_elementwise_fma(vc, sp8(wv1), AN);                          \
  AN = __builtin_elementwise_fma(vp, sp8(wv2), AN);                          \
  AC = __builtin_elementwise_fma(vm, sp8(wv3), AC);                          \
  AC = __builtin_elementwise_fma(vc, sp8(wv4), AC);                          \
  AC = __builtin_elementwise_fma(vp, sp8(wv5), AC);                          \
  AP = __builtin_elementwise_fma(vm, sp8(wv6), AP);                          \
  AP = __builtin_elementwise_fma(vc, sp8(wv7), AP);                          \
  AP = __builtin_elementwise_fma(vp, sp8(wv8), AP);                          \
}

#define ROWFFT(Y, AV) {                                                      \
  float r0=AV[0],r1=AV[1],r2=AV[2],r3=AV[3],r4=AV[4],r5=AV[5],r6=AV[6],r7=AV[7]; \
  float i0=0.f,i1=0.f,i2=0.f,i3=0.f,i4=0.f,i5=0.f,i6=0.f,i7=0.f;             \
  FFT8(r0,r1,r2,r3,r4,r5,r6,r7,i0,i1,i2,i3,i4,i5,i6,i7);                     \
  cr0[Y]=r0; ci0[Y]=i0; cr1[Y]=r1; ci1[Y]=i1; cr2[Y]=r2; ci2[Y]=i2;          \
  cr3[Y]=r3; ci3[Y]=i3; cr4[Y]=r4; ci4[Y]=i4; cr5[Y]=r5; ci5[Y]=i5;          \
  cr6[Y]=r6; ci6[Y]=i6; cr7[Y]=r7; ci7[Y]=i7;                                \
}

#define PH(RE, IM, PIDX) {                                                   \
  const float ph = atan2f(IM, RE);                                           \
  if (first) { phw[(PIDX) * 256] = ph; n1 = fmaf(ph, ph, n1); }              \
  else { const float qv = phw[(PIDX) * 256];                                 \
         dt = fmaf(ph, qv, dt); n2 = fmaf(ph, ph, n2); }                     \
}

#define COLPH(K) {                                                           \
  float r0=cr##K[0],r1=cr##K[1],r2=cr##K[2],r3=cr##K[3],r4=cr##K[4],r5=cr##K[5],r6=cr##K[6],r7=cr##K[7]; \
  float i0=ci##K[0],i1=ci##K[1],i2=ci##K[2],i3=ci##K[3],i4=ci##K[4],i5=ci##K[5],i6=ci##K[6],i7=ci##K[7]; \
  FFT8(r0,r1,r2,r3,r4,r5,r6,r7,i0,i1,i2,i3,i4,i5,i6,i7);                     \
  PH(r0,i0,0*8+K) PH(r1,i1,1*8+K) PH(r2,i2,2*8+K) PH(r3,i3,3*8+K)            \
  PH(r4,i4,4*8+K) PH(r5,i5,5*8+K) PH(r6,i6,6*8+K) PH(r7,i7,7*8+K)            \
}

__global__ __launch_bounds__(256, 2) void k3_conv3_fft(const float* __restrict__ pool2,
                                                       const float* __restrict__ w5t,
                                                       const float* __restrict__ b5,
                                                       float* __restrict__ phase_ws,
                                                       float* __restrict__ maskp,
                                                       int task_base, int T) {
  const int b = blockIdx.x;
  const int tid = threadIdx.x;               // = output channel co
  __shared__ float4 lin4[2048];              // 32 KB: [128ci][8][8] fp32
  __shared__ float rbuf[12];
  float* lin = (float*)lin4;

  const float bias = b5[tid];
  float n1 = 0.f, n2 = 0.f, dt = 0.f;
  float* phw = phase_ws + (size_t)b * 16384 + tid;   // [px][co] px-major

  for (int s = 0; s < 2; ++s) {
    const bool first = (s == 0);
    __syncthreads();
    const float4* src4 = (const float4*)pool2 + (size_t)(s * T + b) * 2048;
    for (int idx = tid; idx < 2048; idx += 256) lin4[idx] = src4[idx];
    __syncthreads();

    f8 a0 = sp8(bias), a1 = sp8(bias), a2 = sp8(bias), a3 = sp8(bias);
    f8 a4 = sp8(bias), a5 = sp8(bias), a6 = sp8(bias), a7 = sp8(bias);
    f8 adump = sp8(0.f);

    for (int ci = 0; ci < 128; ++ci) {
      const float* wvp = w5t + ci * 9 * 256 + tid;   // coalesced per-lane weights
      const float wv0 = wvp[0], wv1 = wvp[256], wv2 = wvp[512];
      const float wv3 = wvp[768], wv4 = wvp[1024], wv5 = wvp[1280];
      const float wv6 = wvp[1536], wv7 = wvp[1792], wv8 = wvp[2048];
      const float* lc = lin + ci * 64;
      CONVROW(0, adump, a0, a1)
      CONVROW(1, a0, a1, a2)
      CONVROW(2, a1, a2, a3)
      CONVROW(3, a2, a3, a4)
      CONVROW(4, a3, a4, a5)
      CONVROW(5, a4, a5, a6)
      CONVROW(6, a5, a6, a7)
      CONVROW(7, a6, a7, adump)
    }

    // FFT2: row FFTs (real) -> column-major named vectors -> col FFTs + phase
    f8 cr0, cr1, cr2, cr3, cr4, cr5, cr6, cr7;
    f8 ci0, ci1, ci2, ci3, ci4, ci5, ci6, ci7;
    ROWFFT(0, a0) ROWFFT(1, a1) ROWFFT(2, a2) ROWFFT(3, a3)
    ROWFFT(4, a4) ROWFFT(5, a5) ROWFFT(6, a6) ROWFFT(7, a7)
    COLPH(0) COLPH(1) COLPH(2) COLPH(3) COLPH(4) COLPH(5) COLPH(6) COLPH(7)
  }

  dt = wave_reduce_sum(dt);
  n1 = wave_reduce_sum(n1);
  n2 = wave_reduce_sum(n2);
  if ((tid & 63) == 0) {
    rbuf[(tid >> 6) * 3 + 0] = dt;
    rbuf[(tid >> 6) * 3 + 1] = n1;
    rbuf[(tid >> 6) * 3 + 2] = n2;
  }
  __syncthreads();
  if (tid == 0) {
    float D = 0.f, A = 0.f, B2 = 0.f;
#pragma unroll
    for (int w = 0; w < 4; ++w) { D += rbuf[w * 3]; A += rbuf[w * 3 + 1]; B2 += rbuf[w * 3 + 2]; }
    const float den = fmaxf(sqrtf(A) * sqrtf(B2), 1e-8f);
    maskp[task_base + b] = ((D / den) >= 0.2f) ? 1.f : 0.f;
  }
}

// ---------------- K4: masked L1 partial reduce ----------------
__global__ __launch_bounds__(256) void k4_l1(const float4* __restrict__ pred2,
                                             const float4* __restrict__ target,
                                             const float* __restrict__ maskp,
                                             float* __restrict__ accum) {
  const int gid = blockIdx.x * 256 + threadIdx.x;
  float part = 0.f;
  for (int e = gid; e < 786432; e += 262144) {
    const int flat = e << 2;
    const int i = flat / 196608;
    const int rem = flat - i * 196608;
    const int pix = rem & 65535;
    const int y = pix >> 8, x = pix & 255;
    const int b = (i << 6) + ((y >> 5) << 3) + (x >> 5);
    if (maskp[b] != 0.f) {
      const float4 p = pred2[e];
      const float4 t = target[e];
      part += fabsf(p.x - t.x) + fabsf(p.y - t.y) + fabsf(p.z - t.z) + fabsf(p.w - t.w);
    }
  }
  part = wave_reduce_sum(part);
  __shared__ float rb[4];
  if ((threadIdx.x & 63) == 0) rb[threadIdx.x >> 6] = part;
  __syncthreads();
  if (threadIdx.x == 0) atomicAdd(accum, rb[0] + rb[1] + rb[2] + rb[3]);
}

// ---------------- K5: finalize ----------------
__global__ __launch_bounds__(256) void k5_final(const float* __restrict__ accum,
                                                const float* __restrict__ maskp,
                                                float* __restrict__ out) {
  float c = 0.f;
  for (int i = threadIdx.x; i < 1024; i += 256) c += maskp[i];
  c = wave_reduce_sum(c);
  __shared__ float rb[4];
  if ((threadIdx.x & 63) == 0) rb[threadIdx.x >> 6] = c;
  __syncthreads();
  if (threadIdx.x == 0) {
    const float cnt = rb[0] + rb[1] + rb[2] + rb[3];
    out[0] = accum[0] / (cnt * 1024.f + 1e-6f);
  }
}

// ---------------------------------------------------------------------------
extern "C" void kernel_launch(void* const* d_in, const int* in_sizes, int n_in,
                              void* d_out, int out_size, void* d_ws, size_t ws_size,
                              hipStream_t stream) {
  (void)in_sizes; (void)n_in; (void)out_size;
  const float* pred1  = (const float*)d_in[0];
  const float* pred2  = (const float*)d_in[1];
  const float* target = (const float*)d_in[2];
  const float* w1 = (const float*)d_in[3];  const float* b1 = (const float*)d_in[4];
  const float* w2 = (const float*)d_in[5];  const float* b2 = (const float*)d_in[6];
  const float* w3 = (const float*)d_in[7];  const float* b3 = (const float*)d_in[8];
  const float* w4 = (const float*)d_in[9];  const float* b4 = (const float*)d_in[10];
  const float* w5 = (const float*)d_in[11]; const float* b5 = (const float*)d_in[12];

  // largest chunk T whose footprint fits: (T*32768 + 294912 + 2048) floats
  int T = 8;
  for (int cand = 1024; cand >= 8; cand >>= 1) {
    const size_t need = ((size_t)cand * 32768 + 294912 + 2048) * sizeof(float);
    if (need <= ws_size) { T = cand; break; }
  }

  float* ws    = (float*)d_ws;
  float* pool1 = ws;                              // T*16384 (also k3 phase buf)
  float* pool2 = ws + (size_t)T * 16384;          // T*16384
  float* w5t   = ws + (size_t)T * 32768;          // 294912
  float* maskp = w5t + 294912;                    // 1024
  float* accum = maskp + 1024;                    // 1
  float* outp  = (float*)d_out;

  k0_zero<<<1, 1, 0, stream>>>(accum);
  k_w5t<<<1152, 256, 0, stream>>>(w5, w5t);

  const int nchunks = 1024 / T;
  for (int c = 0; c < nchunks; ++c) {
    const int base = c * T;
    for (int s = 0; s < 2; ++s) {
      const float* src = s ? target : pred1;
      k1_conv1<<<T, 512, 0, stream>>>(src, w1, b1, w2, b2, pool1, base);
      k2_conv2<<<T, 512, 0, stream>>>(pool1, w3, b3, w4, b4,
                                      pool2 + (size_t)s * T * 8192);
    }
    k3_conv3_fft<<<T, 256, 0, stream>>>(pool2, w5t, b5, pool1, maskp, base, T);
  }
  k4_l1<<<1024, 256, 0, stream>>>((const float4*)pred2, (const float4*)target, maskp, accum);
  k5_final<<<1, 256, 0, stream>>>(accum, maskp, outp);
}

// Round 5
// 6861.516 us; speedup vs baseline: 1.2901x; 1.2901x over previous
//
#include <hip/hip_runtime.h>
#include <math.h>

// ---------------------------------------------------------------------------
// LphaLoss: blockwise VGG19(conv3_1) FFT-phase cosine mask + masked L1.
// fp32 everywhere (mask threshold sim>=0.2 is a discontinuity).
//
// R5 change: k1/k2 at 1024 threads/WG (16 waves/CU, 4/SIMD) — occupancy fix
// for the measured 2-waves/SIMD latency stall (Occ 23.5%, VALUBusy 50%).
//
// ws layout (floats), chunked over T tasks (T adaptive to ws_size):
//   pool1 : [T][64][16][16]  = T*16384   (reused as phase buffer by k3)
//   pool2 : [2][T][128][8][8]= T*16384
//   w5t   : [128*9][256]     = 294912    (transposed conv3 weights)
//   mask  : [1024], accum : [1]
// footprint = (T*32768 + 294912 + 2048) * 4 bytes.
// ---------------------------------------------------------------------------

typedef float f8 __attribute__((ext_vector_type(8)));

__device__ __forceinline__ f8 sp8(float w) { return (f8){w, w, w, w, w, w, w, w}; }

__device__ __forceinline__ float wave_reduce_sum(float v) {
#pragma unroll
  for (int off = 32; off > 0; off >>= 1) v += __shfl_down(v, off);
  return v;
}

__global__ void k0_zero(float* acc) { acc[0] = 0.f; }

// transpose w5 [256co][128ci][9] -> w5t [128ci*9][256co]
__global__ __launch_bounds__(256) void k_w5t(const float* __restrict__ w5,
                                             float* __restrict__ w5t) {
  const int e = blockIdx.x * 256 + threadIdx.x;   // grid 1152*256 = 294912
  const int co = e & 255, t = e >> 8;
  w5t[t * 256 + co] = w5[co * 1152 + t];
}

// ---------------- K1: conv1_1+relu -> conv1_2+relu -> pool1 ----------------
// 1024 threads = 16 waves; 4 output channels per wave in conv1_2.
__global__ __launch_bounds__(1024) void k1_conv1(const float* __restrict__ src,
                                                 const float* __restrict__ w1,
                                                 const float* __restrict__ b1,
                                                 const float* __restrict__ w2,
                                                 const float* __restrict__ b2,
                                                 float* __restrict__ pool1,
                                                 int task_base) {
  const int btl = blockIdx.x;
  const int bt = btl + task_base;
  const int img = bt >> 6, by = (bt >> 3) & 7, bx = bt & 7;
  const int tid = threadIdx.x;

  __shared__ float lin[3 * 34 * 34];
  __shared__ float w1s[64 * 27];
  __shared__ float b1s[64], b2s[64];
  __shared__ float c11[64 * 10 * 34];

  for (int idx = tid; idx < 3 * 34 * 34; idx += 1024) {
    int c = idx / 1156;
    int rm = idx - c * 1156;
    int row = rm / 34;
    int xx = rm - row * 34 - 1;
    int yy = row - 1;
    float v = 0.f;
    if (yy >= 0 && yy < 32 && xx >= 0 && xx < 32) {
      float m = (c == 0) ? 0.485f : (c == 1) ? 0.456f : 0.406f;
      float sd = (c == 0) ? 0.229f : (c == 1) ? 0.224f : 0.225f;
      v = (src[((img * 3 + c) * 256 + (by * 32 + yy)) * 256 + (bx * 32 + xx)] - m) / sd;
    }
    lin[idx] = v;
  }
  for (int idx = tid; idx < 64 * 27; idx += 1024) w1s[idx] = w1[idx];
  if (tid < 64) b1s[tid] = b1[tid];
  else if (tid < 128) b2s[tid - 64] = b2[tid - 64];

  const int cogs = __builtin_amdgcn_readfirstlane(tid >> 6);  // wave id 0..15
  const int lane = tid & 63;
  const int col = lane & 31;    // conv col 0..31 (stride-1 across lanes)
  const int rg = lane >> 5;     // row group 0..1; rows {rg, rg+2, rg+4, rg+6}

  __syncthreads();

  for (int q = 0; q < 4; ++q) {
    const int y0 = q * 8;
    if (q) __syncthreads();
    // conv1_1 + relu into c11 (rows y0-1 .. y0+8, col-halo padded)
    for (int e = tid; e < 64 * 10 * 34; e += 1024) {
      int ch = e / 340;
      int rm = e - ch * 340;
      int r = rm / 34;
      int xp = rm - r * 34;
      int y = y0 - 1 + r;
      int x = xp - 1;
      float v = 0.f;
      if (y >= 0 && y < 32 && x >= 0 && x < 32) {
        float a = b1s[ch];
        const float* wp = &w1s[ch * 27];
#pragma unroll
        for (int ci = 0; ci < 3; ++ci) {
          const float* lp = &lin[ci * 1156 + y * 34 + x];
#pragma unroll
          for (int ky = 0; ky < 3; ++ky)
#pragma unroll
            for (int kx = 0; kx < 3; ++kx)
              a = fmaf(lp[ky * 34 + kx], wp[ci * 9 + ky * 3 + kx], a);
        }
        v = fmaxf(a, 0.f);
      }
      c11[e] = v;
    }
    __syncthreads();

    // conv1_2 (+bias+relu) + 2x2 pool; 4 co per wave
    float acc[4][4];
#pragma unroll
    for (int a = 0; a < 4; ++a)
#pragma unroll
      for (int rr = 0; rr < 4; ++rr) acc[a][rr] = 0.f;

    const float* w2g = w2 + cogs * 4 * 576;
    for (int ci = 0; ci < 64; ++ci) {
      const float* c1b = &c11[ci * 340];
#pragma unroll
      for (int ky = 0; ky < 3; ++ky) {
#pragma unroll
        for (int kx = 0; kx < 3; ++kx) {
          const float* w2c = w2g + ci * 9 + ky * 3 + kx;
          float wv[4];
#pragma unroll
          for (int a = 0; a < 4; ++a) wv[a] = w2c[a * 576];
          const float in0 = c1b[(rg + 0 + ky) * 34 + col + kx];
          const float in1 = c1b[(rg + 2 + ky) * 34 + col + kx];
          const float in2 = c1b[(rg + 4 + ky) * 34 + col + kx];
          const float in3 = c1b[(rg + 6 + ky) * 34 + col + kx];
#pragma unroll
          for (int a = 0; a < 4; ++a) {
            acc[a][0] = fmaf(in0, wv[a], acc[a][0]);
            acc[a][1] = fmaf(in1, wv[a], acc[a][1]);
            acc[a][2] = fmaf(in2, wv[a], acc[a][2]);
            acc[a][3] = fmaf(in3, wv[a], acc[a][3]);
          }
        }
      }
    }
#pragma unroll
    for (int a = 0; a < 4; ++a) {
      const int co = cogs * 4 + a;
      const float bb = b2s[co];
#pragma unroll
      for (int rr = 0; rr < 4; ++rr) {
        float v = fmaxf(acc[a][rr] + bb, 0.f);
        v = fmaxf(v, __shfl_xor(v, 1));    // pool cols (2c, 2c+1)
        v = fmaxf(v, __shfl_xor(v, 32));   // pool rows (2r, 2r+1)
        if (rg == 0 && !(col & 1))
          pool1[((btl * 64 + co) * 16 + q * 4 + rr) * 16 + (col >> 1)] = v;
      }
    }
  }
}

// ---------------- K2: conv2_1+relu -> conv2_2+relu -> pool2 ----------------
// 1024 threads = 16 waves; 8 output channels per wave.
__global__ __launch_bounds__(1024) void k2_conv2(const float* __restrict__ pool1,
                                                 const float* __restrict__ w3,
                                                 const float* __restrict__ b3,
                                                 const float* __restrict__ w4,
                                                 const float* __restrict__ b4,
                                                 float* __restrict__ pool2) {
  const int bt = blockIdx.x;
  const int tid = threadIdx.x;
  __shared__ float lin2[64 * 256];
  __shared__ float c21[128 * 10 * 18];
  __shared__ float b3s[128], b4s[128];

  for (int idx = tid; idx < 64 * 256; idx += 1024) lin2[idx] = pool1[bt * 16384 + idx];
  if (tid < 128) b3s[tid] = b3[tid];
  else if (tid < 256) b4s[tid - 128] = b4[tid - 128];

  const int wv_id = __builtin_amdgcn_readfirstlane(tid >> 6);  // 0..15
  const int lane = tid & 63;

  __syncthreads();

  for (int h = 0; h < 2; ++h) {
    const int y0 = h * 8;
    if (h) __syncthreads();
    // ---- conv2_1 (+bias+relu) into c21 rows y0-1..y0+8; 8 co per wave ----
    {
      const int rq = lane >> 4;
      const int xc = lane & 15;
      const float* w3g = w3 + wv_id * 8 * 576;
      float a21[8][3];
#pragma unroll
      for (int a = 0; a < 8; ++a)
#pragma unroll
        for (int rr = 0; rr < 3; ++rr) a21[a][rr] = 0.f;
      for (int ci = 0; ci < 64; ++ci) {
        const float* l2 = &lin2[ci * 256];
        const float* w3c = w3g + ci * 9;
#pragma unroll
        for (int ky = 0; ky < 3; ++ky) {
#pragma unroll
          for (int kx = 0; kx < 3; ++kx) {
            float wv[8];
#pragma unroll
            for (int a = 0; a < 8; ++a) wv[a] = w3c[a * 576 + ky * 3 + kx];
            const int xin = xc + kx - 1;
            const bool xok = (xin >= 0) && (xin < 16);
#pragma unroll
            for (int rr = 0; rr < 3; ++rr) {
              const int r = rq + rr * 4;
              const int yin = y0 - 2 + r + ky;
              float inv = 0.f;
              if (xok && r < 10 && yin >= 0 && yin < 16) inv = l2[yin * 16 + xin];
#pragma unroll
              for (int a = 0; a < 8; ++a) a21[a][rr] = fmaf(inv, wv[a], a21[a][rr]);
            }
          }
        }
      }
#pragma unroll
      for (int a = 0; a < 8; ++a) {
        const int ch = wv_id * 8 + a;
        const float bb = b3s[ch];
#pragma unroll
        for (int rr = 0; rr < 3; ++rr) {
          const int r = rq + rr * 4;
          if (r < 10) {
            const int y = y0 - 1 + r;
            float v = (y >= 0 && y < 16) ? fmaxf(a21[a][rr] + bb, 0.f) : 0.f;
            c21[(ch * 10 + r) * 18 + xc + 1] = v;
            if (xc == 0) c21[(ch * 10 + r) * 18 + 0] = 0.f;
            if (xc == 15) c21[(ch * 10 + r) * 18 + 17] = 0.f;
          }
        }
      }
    }
    __syncthreads();
    // ---- conv2_2 (+bias+relu) + 2x2 pool; 8 co per wave ----
    {
      const int col2 = lane & 15;   // conv col 0..15
      const int rg2 = lane >> 4;    // 0..3; rows {rg2, rg2+4}
      const float* w4g = w4 + wv_id * 8 * 1152;
      float a22[8][2];
#pragma unroll
      for (int a = 0; a < 8; ++a) { a22[a][0] = 0.f; a22[a][1] = 0.f; }
      for (int ci = 0; ci < 128; ++ci) {
        const float* c2b = &c21[ci * 180];
#pragma unroll
        for (int ky = 0; ky < 3; ++ky) {
#pragma unroll
          for (int kx = 0; kx < 3; ++kx) {
            const float* w4c = w4g + ci * 9 + ky * 3 + kx;
            float wv[8];
#pragma unroll
            for (int a = 0; a < 8; ++a) wv[a] = w4c[a * 1152];
            const float i0 = c2b[(rg2 + 0 + ky) * 18 + col2 + kx];
            const float i1 = c2b[(rg2 + 4 + ky) * 18 + col2 + kx];
#pragma unroll
            for (int a = 0; a < 8; ++a) {
              a22[a][0] = fmaf(i0, wv[a], a22[a][0]);
              a22[a][1] = fmaf(i1, wv[a], a22[a][1]);
            }
          }
        }
      }
#pragma unroll
      for (int a = 0; a < 8; ++a) {
        const int ch = wv_id * 8 + a;
        const float bb = b4s[ch];
#pragma unroll
        for (int j = 0; j < 2; ++j) {
          float v = fmaxf(a22[a][j] + bb, 0.f);
          v = fmaxf(v, __shfl_xor(v, 1));    // pool cols
          v = fmaxf(v, __shfl_xor(v, 16));   // pool rows (rg pairs 0-1, 2-3)
          if (!(rg2 & 1) && !(col2 & 1)) {
            const int prow = h * 4 + j * 2 + (rg2 >> 1);
            pool2[(bt * 128 + ch) * 64 + prow * 8 + (col2 >> 1)] = v;
          }
        }
      }
    }
  }
}

// -------- K3: conv3_1 (both streams) + FFT2 phase + cosine sim -> mask -----
// All per-thread state in NAMED registers (no indexable arrays -> no scratch).
#define C707 0.70710678118654752f

// forward complex FFT8 (matches jnp.fft convention, exp(-i...))
#define FFT8(R0,R1,R2,R3,R4,R5,R6,R7,I0,I1,I2,I3,I4,I5,I6,I7) {              \
  float er0=R0+R4, er1=R0-R4, ei0=I0+I4, ei1=I0-I4;                          \
  float er2=R2+R6, er3=R2-R6, ei2=I2+I6, ei3=I2-I6;                          \
  float E0r=er0+er2, E0i=ei0+ei2, E2r=er0-er2, E2i=ei0-ei2;                  \
  float E1r=er1+ei3, E1i=ei1-er3, E3r=er1-ei3, E3i=ei1+er3;                  \
  float or0=R1+R5, or1=R1-R5, oi0=I1+I5, oi1=I1-I5;                          \
  float or2=R3+R7, or3=R3-R7, oi2=I3+I7, oi3=I3-I7;                          \
  float O0r=or0+or2, O0i=oi0+oi2, O2r=or0-or2, O2i=oi0-oi2;                  \
  float O1r=or1+oi3, O1i=oi1-or3, O3r=or1-oi3, O3i=oi1+or3;                  \
  float T1r=C707*(O1r+O1i), T1i=C707*(O1i-O1r);                              \
  float T2r=O2i, T2i=-O2r;                                                   \
  float T3r=C707*(O3i-O3r), T3i=-C707*(O3r+O3i);                             \
  R0=E0r+O0r; I0=E0i+O0i; R4=E0r-O0r; I4=E0i-O0i;                            \
  R1=E1r+T1r; I1=E1i+T1i; R5=E1r-T1r; I5=E1i-T1i;                            \
  R2=E2r+T2r; I2=E2i+T2i; R6=E2r-T2r; I6=E2i-T2i;                            \
  R3=E3r+T3r; I3=E3i+T3i; R7=E3r-T3r; I7=E3i-T3i;                            \
}

// input row IR contributes to out rows IR+1 (ky=0), IR (ky=1), IR-1 (ky=2)
#define CONVROW(IR, AP, AC, AN) {                                            \
  const float4 lo = *(const float4*)(lc + (IR) * 8);                         \
  const float4 hi = *(const float4*)(lc + (IR) * 8 + 4);                     \
  f8 vm = {0.f, lo.x, lo.y, lo.z, lo.w, hi.x, hi.y, hi.z};                   \
  f8 vc = {lo.x, lo.y, lo.z, lo.w, hi.x, hi.y, hi.z, hi.w};                  \
  f8 vp = {lo.y, lo.z, lo.w, hi.x, hi.y, hi.z, hi.w, 0.f};                   \
  AN = __builtin_elementwise_fma(vm, sp8(wv0), AN);                          \
  AN = __builtin_elementwise_fma(vc, sp8(wv1), AN);                          \
  AN = __builtin_elementwise_fma(vp, sp8(wv2), AN);                          \
  AC = __builtin_elementwise_fma(vm, sp8(wv3), AC);                          \
  AC = __builtin_elementwise_fma(vc, sp8(wv4), AC);                          \
  AC = __builtin_elementwise_fma(vp, sp8(wv5), AC);                          \
  AP = __builtin_elementwise_fma(vm, sp8(wv6), AP);                          \
  AP = __builtin_elementwise_fma(vc, sp8(wv7), AP);                          \
  AP = __builtin_elementwise_fma(vp, sp8(wv8), AP);                          \
}

#define ROWFFT(Y, AV) {                                                      \
  float r0=AV[0],r1=AV[1],r2=AV[2],r3=AV[3],r4=AV[4],r5=AV[5],r6=AV[6],r7=AV[7]; \
  float i0=0.f,i1=0.f,i2=0.f,i3=0.f,i4=0.f,i5=0.f,i6=0.f,i7=0.f;             \
  FFT8(r0,r1,r2,r3,r4,r5,r6,r7,i0,i1,i2,i3,i4,i5,i6,i7);                     \
  cr0[Y]=r0; ci0[Y]=i0; cr1[Y]=r1; ci1[Y]=i1; cr2[Y]=r2; ci2[Y]=i2;          \
  cr3[Y]=r3; ci3[Y]=i3; cr4[Y]=r4; ci4[Y]=i4; cr5[Y]=r5; ci5[Y]=i5;          \
  cr6[Y]=r6; ci6[Y]=i6; cr7[Y]=r7; ci7[Y]=i7;                                \
}

#define PH(RE, IM, PIDX) {                                                   \
  const float ph = atan2f(IM, RE);                                           \
  if (first) { phw[(PIDX) * 256] = ph; n1 = fmaf(ph, ph, n1); }              \
  else { const float qv = phw[(PIDX) * 256];                                 \
         dt = fmaf(ph, qv, dt); n2 = fmaf(ph, ph, n2); }                     \
}

#define COLPH(K) {                                                           \
  float r0=cr##K[0],r1=cr##K[1],r2=cr##K[2],r3=cr##K[3],r4=cr##K[4],r5=cr##K[5],r6=cr##K[6],r7=cr##K[7]; \
  float i0=ci##K[0],i1=ci##K[1],i2=ci##K[2],i3=ci##K[3],i4=ci##K[4],i5=ci##K[5],i6=ci##K[6],i7=ci##K[7]; \
  FFT8(r0,r1,r2,r3,r4,r5,r6,r7,i0,i1,i2,i3,i4,i5,i6,i7);                     \
  PH(r0,i0,0*8+K) PH(r1,i1,1*8+K) PH(r2,i2,2*8+K) PH(r3,i3,3*8+K)            \
  PH(r4,i4,4*8+K) PH(r5,i5,5*8+K) PH(r6,i6,6*8+K) PH(r7,i7,7*8+K)            \
}

__global__ __launch_bounds__(256, 2) void k3_conv3_fft(const float* __restrict__ pool2,
                                                       const float* __restrict__ w5t,
                                                       const float* __restrict__ b5,
                                                       float* __restrict__ phase_ws,
                                                       float* __restrict__ maskp,
                                                       int task_base, int T) {
  const int b = blockIdx.x;
  const int tid = threadIdx.x;               // = output channel co
  __shared__ float4 lin4[2048];              // 32 KB: [128ci][8][8] fp32
  __shared__ float rbuf[12];
  float* lin = (float*)lin4;

  const float bias = b5[tid];
  float n1 = 0.f, n2 = 0.f, dt = 0.f;
  float* phw = phase_ws + (size_t)b * 16384 + tid;   // [px][co] px-major

  for (int s = 0; s < 2; ++s) {
    const bool first = (s == 0);
    __syncthreads();
    const float4* src4 = (const float4*)pool2 + (size_t)(s * T + b) * 2048;
    for (int idx = tid; idx < 2048; idx += 256) lin4[idx] = src4[idx];
    __syncthreads();

    f8 a0 = sp8(bias), a1 = sp8(bias), a2 = sp8(bias), a3 = sp8(bias);
    f8 a4 = sp8(bias), a5 = sp8(bias), a6 = sp8(bias), a7 = sp8(bias);
    f8 adump = sp8(0.f);

    for (int ci = 0; ci < 128; ++ci) {
      const float* wvp = w5t + ci * 9 * 256 + tid;   // coalesced per-lane weights
      const float wv0 = wvp[0], wv1 = wvp[256], wv2 = wvp[512];
      const float wv3 = wvp[768], wv4 = wvp[1024], wv5 = wvp[1280];
      const float wv6 = wvp[1536], wv7 = wvp[1792], wv8 = wvp[2048];
      const float* lc = lin + ci * 64;
      CONVROW(0, adump, a0, a1)
      CONVROW(1, a0, a1, a2)
      CONVROW(2, a1, a2, a3)
      CONVROW(3, a2, a3, a4)
      CONVROW(4, a3, a4, a5)
      CONVROW(5, a4, a5, a6)
      CONVROW(6, a5, a6, a7)
      CONVROW(7, a6, a7, adump)
    }

    // FFT2: row FFTs (real) -> column-major named vectors -> col FFTs + phase
    f8 cr0, cr1, cr2, cr3, cr4, cr5, cr6, cr7;
    f8 ci0, ci1, ci2, ci3, ci4, ci5, ci6, ci7;
    ROWFFT(0, a0) ROWFFT(1, a1) ROWFFT(2, a2) ROWFFT(3, a3)
    ROWFFT(4, a4) ROWFFT(5, a5) ROWFFT(6, a6) ROWFFT(7, a7)
    COLPH(0) COLPH(1) COLPH(2) COLPH(3) COLPH(4) COLPH(5) COLPH(6) COLPH(7)
  }

  dt = wave_reduce_sum(dt);
  n1 = wave_reduce_sum(n1);
  n2 = wave_reduce_sum(n2);
  if ((tid & 63) == 0) {
    rbuf[(tid >> 6) * 3 + 0] = dt;
    rbuf[(tid >> 6) * 3 + 1] = n1;
    rbuf[(tid >> 6) * 3 + 2] = n2;
  }
  __syncthreads();
  if (tid == 0) {
    float D = 0.f, A = 0.f, B2 = 0.f;
#pragma unroll
    for (int w = 0; w < 4; ++w) { D += rbuf[w * 3]; A += rbuf[w * 3 + 1]; B2 += rbuf[w * 3 + 2]; }
    const float den = fmaxf(sqrtf(A) * sqrtf(B2), 1e-8f);
    maskp[task_base + b] = ((D / den) >= 0.2f) ? 1.f : 0.f;
  }
}

// ---------------- K4: masked L1 partial reduce ----------------
__global__ __launch_bounds__(256) void k4_l1(const float4* __restrict__ pred2,
                                             const float4* __restrict__ target,
                                             const float* __restrict__ maskp,
                                             float* __restrict__ accum) {
  const int gid = blockIdx.x * 256 + threadIdx.x;
  float part = 0.f;
  for (int e = gid; e < 786432; e += 262144) {
    const int flat = e << 2;
    const int i = flat / 196608;
    const int rem = flat - i * 196608;
    const int pix = rem & 65535;
    const int y = pix >> 8, x = pix & 255;
    const int b = (i << 6) + ((y >> 5) << 3) + (x >> 5);
    if (maskp[b] != 0.f) {
      const float4 p = pred2[e];
      const float4 t = target[e];
      part += fabsf(p.x - t.x) + fabsf(p.y - t.y) + fabsf(p.z - t.z) + fabsf(p.w - t.w);
    }
  }
  part = wave_reduce_sum(part);
  __shared__ float rb[4];
  if ((threadIdx.x & 63) == 0) rb[threadIdx.x >> 6] = part;
  __syncthreads();
  if (threadIdx.x == 0) atomicAdd(accum, rb[0] + rb[1] + rb[2] + rb[3]);
}

// ---------------- K5: finalize ----------------
__global__ __launch_bounds__(256) void k5_final(const float* __restrict__ accum,
                                                const float* __restrict__ maskp,
                                                float* __restrict__ out) {
  float c = 0.f;
  for (int i = threadIdx.x; i < 1024; i += 256) c += maskp[i];
  c = wave_reduce_sum(c);
  __shared__ float rb[4];
  if ((threadIdx.x & 63) == 0) rb[threadIdx.x >> 6] = c;
  __syncthreads();
  if (threadIdx.x == 0) {
    const float cnt = rb[0] + rb[1] + rb[2] + rb[3];
    out[0] = accum[0] / (cnt * 1024.f + 1e-6f);
  }
}

// ---------------------------------------------------------------------------
extern "C" void kernel_launch(void* const* d_in, const int* in_sizes, int n_in,
                              void* d_out, int out_size, void* d_ws, size_t ws_size,
                              hipStream_t stream) {
  (void)in_sizes; (void)n_in; (void)out_size;
  const float* pred1  = (const float*)d_in[0];
  const float* pred2  = (const float*)d_in[1];
  const float* target = (const float*)d_in[2];
  const float* w1 = (const float*)d_in[3];  const float* b1 = (const float*)d_in[4];
  const float* w2 = (const float*)d_in[5];  const float* b2 = (const float*)d_in[6];
  const float* w3 = (const float*)d_in[7];  const float* b3 = (const float*)d_in[8];
  const float* w4 = (const float*)d_in[9];  const float* b4 = (const float*)d_in[10];
  const float* w5 = (const float*)d_in[11]; const float* b5 = (const float*)d_in[12];

  // largest chunk T whose footprint fits: (T*32768 + 294912 + 2048) floats
  int T = 8;
  for (int cand = 1024; cand >= 8; cand >>= 1) {
    const size_t need = ((size_t)cand * 32768 + 294912 + 2048) * sizeof(float);
    if (need <= ws_size) { T = cand; break; }
  }

  float* ws    = (float*)d_ws;
  float* pool1 = ws;                              // T*16384 (also k3 phase buf)
  float* pool2 = ws + (size_t)T * 16384;          // T*16384
  float* w5t   = ws + (size_t)T * 32768;          // 294912
  float* maskp = w5t + 294912;                    // 1024
  float* accum = maskp + 1024;                    // 1
  float* outp  = (float*)d_out;

  k0_zero<<<1, 1, 0, stream>>>(accum);
  k_w5t<<<1152, 256, 0, stream>>>(w5, w5t);

  const int nchunks = 1024 / T;
  for (int c = 0; c < nchunks; ++c) {
    const int base = c * T;
    for (int s = 0; s < 2; ++s) {
      const float* src = s ? target : pred1;
      k1_conv1<<<T, 1024, 0, stream>>>(src, w1, b1, w2, b2, pool1, base);
      k2_conv2<<<T, 1024, 0, stream>>>(pool1, w3, b3, w4, b4,
                                       pool2 + (size_t)s * T * 8192);
    }
    k3_conv3_fft<<<T, 256, 0, stream>>>(pool2, w5t, b5, pool1, maskp, base, T);
  }
  k4_l1<<<1024, 256, 0, stream>>>((const float4*)pred2, (const float4*)target, maskp, accum);
  k5_final<<<1, 256, 0, stream>>>(accum, maskp, outp);
}

// Round 6
// 6468.684 us; speedup vs baseline: 1.3684x; 1.0607x over previous
//
#include <hip/hip_runtime.h>
#include <math.h>

// ---------------------------------------------------------------------------
// LphaLoss: blockwise VGG19(conv3_1) FFT-phase cosine mask + masked L1.
// R6: k2 rewritten as bf16x3-split MFMA (fp32-accurate; mask threshold safe).
//
// ws layout (floats), chunked over T tasks:
//   pool1 : [T][64][16][16]   = T*16384   (reused as phase buffer by k3)
//   pool2 : [2][T][128][8][8] = T*16384   (layout per block: [128 ch][64 s])
//   w5t   : [128*9][256]      = 294912    (transposed conv3 weights, fp32)
//   w3t   : [9][128co][64ci]  hi+lo bf16  (73728 u16 each)
//   w4t   : [9][128co][128ci] hi+lo bf16  (147456 u16 each)
//   mask  : [1024], accum : [1]
// ---------------------------------------------------------------------------

typedef float f8 __attribute__((ext_vector_type(8)));
typedef float f4v __attribute__((ext_vector_type(4)));
typedef short s8v __attribute__((ext_vector_type(8)));
typedef unsigned short u16;

__device__ __forceinline__ f8 sp8(float w) { return (f8){w, w, w, w, w, w, w, w}; }

__device__ __forceinline__ u16 bf16rn(float f) {
  union { float f; unsigned u; } x; x.f = f;
  return (u16)((x.u + 0x7FFFu + ((x.u >> 16) & 1u)) >> 16);
}
__device__ __forceinline__ float bfbits2f(u16 b) {
  union { float f; unsigned u; } x; x.u = ((unsigned)b) << 16;
  return x.f;
}

__device__ __forceinline__ float wave_reduce_sum(float v) {
#pragma unroll
  for (int off = 32; off > 0; off >>= 1) v += __shfl_down(v, off);
  return v;
}

__global__ void k0_zero(float* acc) { acc[0] = 0.f; }

// transpose w5 [256co][128ci][9] -> w5t [128ci*9][256co]
__global__ __launch_bounds__(256) void k_w5t(const float* __restrict__ w5,
                                             float* __restrict__ w5t) {
  const int e = blockIdx.x * 256 + threadIdx.x;   // grid 1152*256 = 294912
  const int co = e & 255, t = e >> 8;
  w5t[t * 256 + co] = w5[co * 1152 + t];
}

// split+transpose w3 [128co][64ci][9] -> [9][co][ci] hi/lo ; w4 likewise
__global__ __launch_bounds__(256) void k_wprep(const float* __restrict__ w3,
                                               const float* __restrict__ w4,
                                               u16* __restrict__ w3th, u16* __restrict__ w3tl,
                                               u16* __restrict__ w4th, u16* __restrict__ w4tl) {
  const int e = blockIdx.x * 256 + threadIdx.x;   // 864*256 = 221184
  float v; int o; u16* ph; u16* pl;
  if (e < 73728) {
    const int tap = e >> 13, r = e & 8191, co = r >> 6, ci = r & 63;
    v = w3[co * 576 + ci * 9 + tap]; o = e; ph = w3th; pl = w3tl;
  } else {
    const int e2 = e - 73728;
    const int tap = e2 >> 14, r = e2 & 16383, co = r >> 7, ci = r & 127;
    v = w4[co * 1152 + ci * 9 + tap]; o = e2; ph = w4th; pl = w4tl;
  }
  const u16 hb = bf16rn(v);
  const u16 lb = bf16rn(v - bfbits2f(hb));
  ph[o] = hb; pl[o] = lb;
}

// ---------------- K1: conv1_1+relu -> conv1_2+relu -> pool1 ----------------
// (unchanged from R5 — validated)
__global__ __launch_bounds__(1024) void k1_conv1(const float* __restrict__ src,
                                                 const float* __restrict__ w1,
                                                 const float* __restrict__ b1,
                                                 const float* __restrict__ w2,
                                                 const float* __restrict__ b2,
                                                 float* __restrict__ pool1,
                                                 int task_base) {
  const int btl = blockIdx.x;
  const int bt = btl + task_base;
  const int img = bt >> 6, by = (bt >> 3) & 7, bx = bt & 7;
  const int tid = threadIdx.x;

  __shared__ float lin[3 * 34 * 34];
  __shared__ float w1s[64 * 27];
  __shared__ float b1s[64], b2s[64];
  __shared__ float c11[64 * 10 * 34];

  for (int idx = tid; idx < 3 * 34 * 34; idx += 1024) {
    int c = idx / 1156;
    int rm = idx - c * 1156;
    int row = rm / 34;
    int xx = rm - row * 34 - 1;
    int yy = row - 1;
    float v = 0.f;
    if (yy >= 0 && yy < 32 && xx >= 0 && xx < 32) {
      float m = (c == 0) ? 0.485f : (c == 1) ? 0.456f : 0.406f;
      float sd = (c == 0) ? 0.229f : (c == 1) ? 0.224f : 0.225f;
      v = (src[((img * 3 + c) * 256 + (by * 32 + yy)) * 256 + (bx * 32 + xx)] - m) / sd;
    }
    lin[idx] = v;
  }
  for (int idx = tid; idx < 64 * 27; idx += 1024) w1s[idx] = w1[idx];
  if (tid < 64) b1s[tid] = b1[tid];
  else if (tid < 128) b2s[tid - 64] = b2[tid - 64];

  const int cogs = __builtin_amdgcn_readfirstlane(tid >> 6);  // wave id 0..15
  const int lane = tid & 63;
  const int col = lane & 31;
  const int rg = lane >> 5;

  __syncthreads();

  for (int q = 0; q < 4; ++q) {
    const int y0 = q * 8;
    if (q) __syncthreads();
    for (int e = tid; e < 64 * 10 * 34; e += 1024) {
      int ch = e / 340;
      int rm = e - ch * 340;
      int r = rm / 34;
      int xp = rm - r * 34;
      int y = y0 - 1 + r;
      int x = xp - 1;
      float v = 0.f;
      if (y >= 0 && y < 32 && x >= 0 && x < 32) {
        float a = b1s[ch];
        const float* wp = &w1s[ch * 27];
#pragma unroll
        for (int ci = 0; ci < 3; ++ci) {
          const float* lp = &lin[ci * 1156 + y * 34 + x];
#pragma unroll
          for (int ky = 0; ky < 3; ++ky)
#pragma unroll
            for (int kx = 0; kx < 3; ++kx)
              a = fmaf(lp[ky * 34 + kx], wp[ci * 9 + ky * 3 + kx], a);
        }
        v = fmaxf(a, 0.f);
      }
      c11[e] = v;
    }
    __syncthreads();

    float acc[4][4];
#pragma unroll
    for (int a = 0; a < 4; ++a)
#pragma unroll
      for (int rr = 0; rr < 4; ++rr) acc[a][rr] = 0.f;

    const float* w2g = w2 + cogs * 4 * 576;
    for (int ci = 0; ci < 64; ++ci) {
      const float* c1b = &c11[ci * 340];
#pragma unroll
      for (int ky = 0; ky < 3; ++ky) {
#pragma unroll
        for (int kx = 0; kx < 3; ++kx) {
          const float* w2c = w2g + ci * 9 + ky * 3 + kx;
          float wv[4];
#pragma unroll
          for (int a = 0; a < 4; ++a) wv[a] = w2c[a * 576];
          const float in0 = c1b[(rg + 0 + ky) * 34 + col + kx];
          const float in1 = c1b[(rg + 2 + ky) * 34 + col + kx];
          const float in2 = c1b[(rg + 4 + ky) * 34 + col + kx];
          const float in3 = c1b[(rg + 6 + ky) * 34 + col + kx];
#pragma unroll
          for (int a = 0; a < 4; ++a) {
            acc[a][0] = fmaf(in0, wv[a], acc[a][0]);
            acc[a][1] = fmaf(in1, wv[a], acc[a][1]);
            acc[a][2] = fmaf(in2, wv[a], acc[a][2]);
            acc[a][3] = fmaf(in3, wv[a], acc[a][3]);
          }
        }
      }
    }
#pragma unroll
    for (int a = 0; a < 4; ++a) {
      const int co = cogs * 4 + a;
      const float bb = b2s[co];
#pragma unroll
      for (int rr = 0; rr < 4; ++rr) {
        float v = fmaxf(acc[a][rr] + bb, 0.f);
        v = fmaxf(v, __shfl_xor(v, 1));
        v = fmaxf(v, __shfl_xor(v, 32));
        if (rg == 0 && !(col & 1))
          pool1[((btl * 64 + co) * 16 + q * 4 + rr) * 16 + (col >> 1)] = v;
      }
    }
  }
}

// ---------------- K2: MFMA bf16x3 conv2_1 -> conv2_2 -> pool ----------------
// 1024 thr = 16 waves; wave w owns a 2-row x 8-col pixel tile (ty=w>>1, tx=w&1).
// A-frag: lane&15 = m (pixel in tile), lane>>4 = k-granule; 8 ci per b128 read.
// B-frag: lane&15 = co-in-tile, lane>>4 = k-granule; from [tap][co][ci] global.
// C-frag: col = lane&15 (co), row = (lane>>4)*4+reg (pixel).
__global__ __launch_bounds__(1024) void k2_mfma(const float* __restrict__ pool1,
                                                const u16* __restrict__ w3th,
                                                const u16* __restrict__ w3tl,
                                                const u16* __restrict__ w4th,
                                                const u16* __restrict__ w4tl,
                                                const float* __restrict__ b3,
                                                const float* __restrict__ b4,
                                                float* __restrict__ pool2) {
  const int bt = blockIdx.x;
  const int tid = threadIdx.x;
  __shared__ u16 umem[65536];               // 128 KB union
  __shared__ float b3s[128], b4s[128];
  u16* img1h = umem;                        // [256 pix][64 ci] granule-swizzled
  u16* img1l = umem + 16384;
  u16* img2h = umem;                        // [256 pix][128 ci]
  u16* img2l = umem + 32768;
  float* pbuf = (float*)umem;               // [128 ch][64 s]

  // ---- phase 0: stage pool1 -> img1 (hi/lo split, swizzled) ----
  for (int e = tid; e < 16384; e += 1024) {
    const int ci = e >> 8, pix = e & 255;
    const float v = pool1[bt * 16384 + e];
    const u16 hb = bf16rn(v);
    const u16 lb = bf16rn(v - bfbits2f(hb));
    const int idx = pix * 64 + ((((ci >> 3) ^ pix) & 7) << 3) + (ci & 7);
    img1h[idx] = hb; img1l[idx] = lb;
  }
  if (tid < 128) b3s[tid] = b3[tid];
  else if (tid < 256) b4s[tid - 128] = b4[tid - 128];
  __syncthreads();

  const int w = tid >> 6, lane = tid & 63;
  const int ty = w >> 1, tx = w & 1;
  const int moff = lane & 15, grp = lane >> 4, col = moff;
  const int ar = moff >> 3, ac = moff & 7;    // pixel row-in-pair / col-in-8

  f4v acc[8];
#pragma unroll
  for (int n = 0; n < 8; ++n) acc[n] = (f4v){0.f, 0.f, 0.f, 0.f};

  // ---- phase 1: conv2_1 MFMA (K = 9 taps x 64 ci) ----
#pragma unroll
  for (int tap = 0; tap < 9; ++tap) {
    const int dy = tap / 3, dx = tap - dy * 3;
    const int yin = ty * 2 + ar + dy - 1;
    const int xin = tx * 8 + ac + dx - 1;
    const bool vld = ((unsigned)yin < 16u) && ((unsigned)xin < 16u);
    const int pix = vld ? yin * 16 + xin : 0;
#pragma unroll
    for (int ks = 0; ks < 2; ++ks) {
      const int gi = pix * 64 + (((((ks << 2) + grp) ^ xin) & 7) << 3);
      s8v ah = *(const s8v*)(img1h + gi);
      s8v al = *(const s8v*)(img1l + gi);
      if (!vld) { ah = (s8v){0,0,0,0,0,0,0,0}; al = (s8v){0,0,0,0,0,0,0,0}; }
      const int wb = (tap * 128 + col) * 64 + (ks << 5) + (grp << 3);
#pragma unroll
      for (int n = 0; n < 8; ++n) {
        const s8v bh = *(const s8v*)(w3th + wb + n * 1024);
        const s8v bl = *(const s8v*)(w3tl + wb + n * 1024);
        acc[n] = __builtin_amdgcn_mfma_f32_16x16x32_bf16(ah, bh, acc[n], 0, 0, 0);
        acc[n] = __builtin_amdgcn_mfma_f32_16x16x32_bf16(ah, bl, acc[n], 0, 0, 0);
        acc[n] = __builtin_amdgcn_mfma_f32_16x16x32_bf16(al, bh, acc[n], 0, 0, 0);
      }
    }
  }
  __syncthreads();   // img1 reads complete (img2 aliases img1)

  // ---- phase 2: bias+relu, split, write img2 ----
#pragma unroll
  for (int n = 0; n < 8; ++n) {
    const float bb = b3s[n * 16 + col];
#pragma unroll
    for (int r = 0; r < 4; ++r) {
      const int mo = grp * 4 + r;
      const int x = tx * 8 + (mo & 7);
      const int pix = (ty * 2 + (mo >> 3)) * 16 + x;
      float v = fmaxf(acc[n][r] + bb, 0.f);
      const u16 hb = bf16rn(v);
      const u16 lb = bf16rn(v - bfbits2f(hb));
      const int co = n * 16 + col;
      const int idx = pix * 128 + ((((co >> 3) ^ x) & 15) << 3) + (co & 7);
      img2h[idx] = hb; img2l[idx] = lb;
    }
  }
  __syncthreads();

  // ---- phase 3: conv2_2 MFMA (K = 9 taps x 128 ci) ----
#pragma unroll
  for (int n = 0; n < 8; ++n) acc[n] = (f4v){0.f, 0.f, 0.f, 0.f};
#pragma unroll
  for (int tap = 0; tap < 9; ++tap) {
    const int dy = tap / 3, dx = tap - dy * 3;
    const int yin = ty * 2 + ar + dy - 1;
    const int xin = tx * 8 + ac + dx - 1;
    const bool vld = ((unsigned)yin < 16u) && ((unsigned)xin < 16u);
    const int pix = vld ? yin * 16 + xin : 0;
#pragma unroll
    for (int ks = 0; ks < 4; ++ks) {
      const int gi = pix * 128 + (((((ks << 2) + grp) ^ xin) & 15) << 3);
      s8v ah = *(const s8v*)(img2h + gi);
      s8v al = *(const s8v*)(img2l + gi);
      if (!vld) { ah = (s8v){0,0,0,0,0,0,0,0}; al = (s8v){0,0,0,0,0,0,0,0}; }
      const int wb = (tap * 128 + col) * 128 + (ks << 5) + (grp << 3);
#pragma unroll
      for (int n = 0; n < 8; ++n) {
        const s8v bh = *(const s8v*)(w4th + wb + n * 2048);
        const s8v bl = *(const s8v*)(w4tl + wb + n * 2048);
        acc[n] = __builtin_amdgcn_mfma_f32_16x16x32_bf16(ah, bh, acc[n], 0, 0, 0);
        acc[n] = __builtin_amdgcn_mfma_f32_16x16x32_bf16(ah, bl, acc[n], 0, 0, 0);
        acc[n] = __builtin_amdgcn_mfma_f32_16x16x32_bf16(al, bh, acc[n], 0, 0, 0);
      }
    }
  }
  __syncthreads();   // img2 reads complete (pbuf aliases img2)

  // ---- phase 4: bias+relu + in-register 2x2 pool -> pbuf ----
#pragma unroll
  for (int n = 0; n < 8; ++n) {
    const float bb = b4s[n * 16 + col];
    float v0 = fmaxf(acc[n][0] + bb, 0.f);
    float v1 = fmaxf(acc[n][1] + bb, 0.f);
    float v2 = fmaxf(acc[n][2] + bb, 0.f);
    float v3 = fmaxf(acc[n][3] + bb, 0.f);
    float h0 = fmaxf(v0, v1), h1 = fmaxf(v2, v3);   // horizontal pairs
    h0 = fmaxf(h0, __shfl_xor(h0, 32));             // vertical (row y <-> y+1)
    h1 = fmaxf(h1, __shfl_xor(h1, 32));
    if (grp < 2) {
      const int ch = n * 16 + col;
      const int s = ty * 8 + tx * 4 + (grp & 1) * 2;
      pbuf[ch * 64 + s] = h0;
      pbuf[ch * 64 + s + 1] = h1;
    }
  }
  __syncthreads();

  // ---- phase 5: coalesced pbuf -> pool2 ([128 ch][64 s] per block) ----
  for (int e = tid; e < 8192; e += 1024)
    pool2[bt * 8192 + e] = pbuf[e];
}

// -------- K3: conv3_1 (both streams) + FFT2 phase + cosine sim -> mask -----
#define C707 0.70710678118654752f

#define FFT8(R0,R1,R2,R3,R4,R5,R6,R7,I0,I1,I2,I3,I4,I5,I6,I7) {              \
  float er0=R0+R4, er1=R0-R4, ei0=I0+I4, ei1=I0-I4;                          \
  float er2=R2+R6, er3=R2-R6, ei2=I2+I6, ei3=I2-I6;                          \
  float E0r=er0+er2, E0i=ei0+ei2, E2r=er0-er2, E2i=ei0-ei2;                  \
  float E1r=er1+ei3, E1i=ei1-er3, E3r=er1-ei3, E3i=ei1+er3;                  \
  float or0=R1+R5, or1=R1-R5, oi0=I1+I5, oi1=I1-I5;                          \
  float or2=R3+R7, or3=R3-R7, oi2=I3+I7, oi3=I3-I7;                          \
  float O0r=or0+or2, O0i=oi0+oi2, O2r=or0-or2, O2i=oi0-oi2;                  \
  float O1r=or1+oi3, O1i=oi1-or3, O3r=or1-oi3, O3i=oi1+or3;                  \
  float T1r=C707*(O1r+O1i), T1i=C707*(O1i-O1r);                              \
  float T2r=O2i, T2i=-O2r;                                                   \
  float T3r=C707*(O3i-O3r), T3i=-C707*(O3r+O3i);                             \
  R0=E0r+O0r; I0=E0i+O0i; R4=E0r-O0r; I4=E0i-O0i;                            \
  R1=E1r+T1r; I1=E1i+T1i; R5=E1r-T1r; I5=E1i-T1i;                            \
  R2=E2r+T2r; I2=E2i+T2i; R6=E2r-T2r; I6=E2i-T2i;                            \
  R3=E3r+T3r; I3=E3i+T3i; R7=E3r-T3r; I7=E3i-T7i_dummy; (void)0;             \
}
// NOTE: macro above must not contain typos — define cleanly below instead.
#undef FFT8
#define FFT8(R0,R1,R2,R3,R4,R5,R6,R7,I0,I1,I2,I3,I4,I5,I6,I7) {              \
  float er0=R0+R4, er1=R0-R4, ei0=I0+I4, ei1=I0-I4;                          \
  float er2=R2+R6, er3=R2-R6, ei2=I2+I6, ei3=I2-I6;                          \
  float E0r=er0+er2, E0i=ei0+ei2, E2r=er0-er2, E2i=ei0-ei2;                  \
  float E1r=er1+ei3, E1i=ei1-er3, E3r=er1-ei3, E3i=ei1+er3;                  \
  float or0=R1+R5, or1=R1-R5, oi0=I1+I5, oi1=I1-I5;                          \
  float or2=R3+R7, or3=R3-R7, oi2=I3+I7, oi3=I3-I7;                          \
  float O0r=or0+or2, O0i=oi0+oi2, O2r=or0-or2, O2i=oi0-oi2;                  \
  float O1r=or1+oi3, O1i=oi1-or3, O3r=or1-oi3, O3i=oi1+or3;                  \
  float T1r=C707*(O1r+O1i), T1i=C707*(O1i-O1r);                              \
  float T2r=O2i, T2i=-O2r;                                                   \
  float T3r=C707*(O3i-O3r), T3i=-C707*(O3r+O3i);                             \
  R0=E0r+O0r; I0=E0i+O0i; R4=E0r-O0r; I4=E0i-O0i;                            \
  R1=E1r+T1r; I1=E1i+T1i; R5=E1r-T1r; I5=E1i-T1i;                            \
  R2=E2r+T2r; I2=E2i+T2i; R6=E2r-T2r; I6=E2i-T2i;                            \
  R3=E3r+T3r; I3=E3i+T3i; R7=E3r-T3r; I7=E3i-T3i;                            \
}

#define CONVROW(IR, AP, AC, AN) {                                            \
  const float4 lo = *(const float4*)(lc + (IR) * 8);                         \
  const float4 hi = *(const float4*)(lc + (IR) * 8 + 4);                     \
  f8 vm = {0.f, lo.x, lo.y, lo.z, lo.w, hi.x, hi.y, hi.z};                   \
  f8 vc = {lo.x, lo.y, lo.z, lo.w, hi.x, hi.y, hi.z, hi.w};                  \
  f8 vp = {lo.y, lo.z, lo.w, hi.x, hi.y, hi.z, hi.w, 0.f};                   \
  AN = __builtin_elementwise_fma(vm, sp8(wv0), AN);                          \
  AN = __builtin_elementwise_fma(vc, sp8(wv1), AN);                          \
  AN = __builtin_elementwise_fma(vp, sp8(wv2), AN);                          \
  AC = __builtin_elementwise_fma(vm, sp8(wv3), AC);                          \
  AC = __builtin_elementwise_fma(vc, sp8(wv4), AC);                          \
  AC = __builtin_elementwise_fma(vp, sp8(wv5), AC);                          \
  AP = __builtin_elementwise_fma(vm, sp8(wv6), AP);                          \
  AP = __builtin_elementwise_fma(vc, sp8(wv7), AP);                          \
  AP = __builtin_elementwise_fma(vp, sp8(wv8), AP);                          \
}

#define ROWFFT(Y, AV) {                                                      \
  float r0=AV[0],r1=AV[1],r2=AV[2],r3=AV[3],r4=AV[4],r5=AV[5],r6=AV[6],r7=AV[7]; \
  float i0=0.f,i1=0.f,i2=0.f,i3=0.f,i4=0.f,i5=0.f,i6=0.f,i7=0.f;             \
  FFT8(r0,r1,r2,r3,r4,r5,r6,r7,i0,i1,i2,i3,i4,i5,i6,i7);                     \
  cr0[Y]=r0; ci0[Y]=i0; cr1[Y]=r1; ci1[Y]=i1; cr2[Y]=r2; ci2[Y]=i2;          \
  cr3[Y]=r3; ci3[Y]=i3; cr4[Y]=r4; ci4[Y]=i4; cr5[Y]=r5; ci5[Y]=i5;          \
  cr6[Y]=r6; ci6[Y]=i6; cr7[Y]=r7; ci7[Y]=i7;                                \
}

#define PH(RE, IM, PIDX) {                                                   \
  const float ph = atan2f(IM, RE);                                           \
  if (first) { phw[(PIDX) * 256] = ph; n1 = fmaf(ph, ph, n1); }              \
  else { const float qv = phw[(PIDX) * 256];                                 \
         dt = fmaf(ph, qv, dt); n2 = fmaf(ph, ph, n2); }                     \
}

#define COLPH(K) {                                                           \
  float r0=cr##K[0],r1=cr##K[1],r2=cr##K[2],r3=cr##K[3],r4=cr##K[4],r5=cr##K[5],r6=cr##K[6],r7=cr##K[7]; \
  float i0=ci##K[0],i1=ci##K[1],i2=ci##K[2],i3=ci##K[3],i4=ci##K[4],i5=ci##K[5],i6=ci##K[6],i7=ci##K[7]; \
  FFT8(r0,r1,r2,r3,r4,r5,r6,r7,i0,i1,i2,i3,i4,i5,i6,i7);                     \
  PH(r0,i0,0*8+K) PH(r1,i1,1*8+K) PH(r2,i2,2*8+K) PH(r3,i3,3*8+K)            \
  PH(r4,i4,4*8+K) PH(r5,i5,5*8+K) PH(r6,i6,6*8+K) PH(r7,i7,7*8+K)            \
}

__global__ __launch_bounds__(256, 2) void k3_conv3_fft(const float* __restrict__ pool2,
                                                       const float* __restrict__ w5t,
                                                       const float* __restrict__ b5,
                                                       float* __restrict__ phase_ws,
                                                       float* __restrict__ maskp,
                                                       int task_base, int T) {
  const int b = blockIdx.x;
  const int tid = threadIdx.x;               // = output channel co
  __shared__ float4 lin4[2048];              // 32 KB: [128ci][8][8] fp32
  __shared__ float rbuf[12];
  float* lin = (float*)lin4;

  const float bias = b5[tid];
  float n1 = 0.f, n2 = 0.f, dt = 0.f;
  float* phw = phase_ws + (size_t)b * 16384 + tid;   // [px][co] px-major

  for (int s = 0; s < 2; ++s) {
    const bool first = (s == 0);
    __syncthreads();
    const float4* src4 = (const float4*)pool2 + (size_t)(s * T + b) * 2048;
    for (int idx = tid; idx < 2048; idx += 256) lin4[idx] = src4[idx];
    __syncthreads();

    f8 a0 = sp8(bias), a1 = sp8(bias), a2 = sp8(bias), a3 = sp8(bias);
    f8 a4 = sp8(bias), a5 = sp8(bias), a6 = sp8(bias), a7 = sp8(bias);
    f8 adump = sp8(0.f);

    for (int ci = 0; ci < 128; ++ci) {
      const float* wvp = w5t + ci * 9 * 256 + tid;
      const float wv0 = wvp[0], wv1 = wvp[256], wv2 = wvp[512];
      const float wv3 = wvp[768], wv4 = wvp[1024], wv5 = wvp[1280];
      const float wv6 = wvp[1536], wv7 = wvp[1792], wv8 = wvp[2048];
      const float* lc = lin + ci * 64;
      CONVROW(0, adump, a0, a1)
      CONVROW(1, a0, a1, a2)
      CONVROW(2, a1, a2, a3)
      CONVROW(3, a2, a3, a4)
      CONVROW(4, a3, a4, a5)
      CONVROW(5, a4, a5, a6)
      CONVROW(6, a5, a6, a7)
      CONVROW(7, a6, a7, adump)
    }

    f8 cr0, cr1, cr2, cr3, cr4, cr5, cr6, cr7;
    f8 ci0, ci1, ci2, ci3, ci4, ci5, ci6, ci7;
    ROWFFT(0, a0) ROWFFT(1, a1) ROWFFT(2, a2) ROWFFT(3, a3)
    ROWFFT(4, a4) ROWFFT(5, a5) ROWFFT(6, a6) ROWFFT(7, a7)
    COLPH(0) COLPH(1) COLPH(2) COLPH(3) COLPH(4) COLPH(5) COLPH(6) COLPH(7)
  }

  dt = wave_reduce_sum(dt);
  n1 = wave_reduce_sum(n1);
  n2 = wave_reduce_sum(n2);
  if ((tid & 63) == 0) {
    rbuf[(tid >> 6) * 3 + 0] = dt;
    rbuf[(tid >> 6) * 3 + 1] = n1;
    rbuf[(tid >> 6) * 3 + 2] = n2;
  }
  __syncthreads();
  if (tid == 0) {
    float D = 0.f, A = 0.f, B2 = 0.f;
#pragma unroll
    for (int w = 0; w < 4; ++w) { D += rbuf[w * 3]; A += rbuf[w * 3 + 1]; B2 += rbuf[w * 3 + 2]; }
    const float den = fmaxf(sqrtf(A) * sqrtf(B2), 1e-8f);
    maskp[task_base + b] = ((D / den) >= 0.2f) ? 1.f : 0.f;
  }
}

// ---------------- K4: masked L1 partial reduce ----------------
__global__ __launch_bounds__(256) void k4_l1(const float4* __restrict__ pred2,
                                             const float4* __restrict__ target,
                                             const float* __restrict__ maskp,
                                             float* __restrict__ accum) {
  const int gid = blockIdx.x * 256 + threadIdx.x;
  float part = 0.f;
  for (int e = gid; e < 786432; e += 262144) {
    const int flat = e << 2;
    const int i = flat / 196608;
    const int rem = flat - i * 196608;
    const int pix = rem & 65535;
    const int y = pix >> 8, x = pix & 255;
    const int b = (i << 6) + ((y >> 5) << 3) + (x >> 5);
    if (maskp[b] != 0.f) {
      const float4 p = pred2[e];
      const float4 t = target[e];
      part += fabsf(p.x - t.x) + fabsf(p.y - t.y) + fabsf(p.z - t.z) + fabsf(p.w - t.w);
    }
  }
  part = wave_reduce_sum(part);
  __shared__ float rb[4];
  if ((threadIdx.x & 63) == 0) rb[threadIdx.x >> 6] = part;
  __syncthreads();
  if (threadIdx.x == 0) atomicAdd(accum, rb[0] + rb[1] + rb[2] + rb[3]);
}

// ---------------- K5: finalize ----------------
__global__ __launch_bounds__(256) void k5_final(const float* __restrict__ accum,
                                                const float* __restrict__ maskp,
                                                float* __restrict__ out) {
  float c = 0.f;
  for (int i = threadIdx.x; i < 1024; i += 256) c += maskp[i];
  c = wave_reduce_sum(c);
  __shared__ float rb[4];
  if ((threadIdx.x & 63) == 0) rb[threadIdx.x >> 6] = c;
  __syncthreads();
  if (threadIdx.x == 0) {
    const float cnt = rb[0] + rb[1] + rb[2] + rb[3];
    out[0] = accum[0] / (cnt * 1024.f + 1e-6f);
  }
}

// ---------------------------------------------------------------------------
extern "C" void kernel_launch(void* const* d_in, const int* in_sizes, int n_in,
                              void* d_out, int out_size, void* d_ws, size_t ws_size,
                              hipStream_t stream) {
  (void)in_sizes; (void)n_in; (void)out_size;
  const float* pred1  = (const float*)d_in[0];
  const float* pred2  = (const float*)d_in[1];
  const float* target = (const float*)d_in[2];
  const float* w1 = (const float*)d_in[3];  const float* b1 = (const float*)d_in[4];
  const float* w2 = (const float*)d_in[5];  const float* b2 = (const float*)d_in[6];
  const float* w3 = (const float*)d_in[7];  const float* b3 = (const float*)d_in[8];
  const float* w4 = (const float*)d_in[9];  const float* b4 = (const float*)d_in[10];
  const float* w5 = (const float*)d_in[11]; const float* b5 = (const float*)d_in[12];

  // footprint(T) = (T*32768 + 294912 + 221184 + 2048) floats
  int T = 8;
  for (int cand = 1024; cand >= 8; cand >>= 1) {
    const size_t need = ((size_t)cand * 32768 + 294912 + 221184 + 2048) * sizeof(float);
    if (need <= ws_size) { T = cand; break; }
  }

  float* ws    = (float*)d_ws;
  float* pool1 = ws;                              // T*16384 (also k3 phase buf)
  float* pool2 = ws + (size_t)T * 16384;          // T*16384
  float* w5t   = ws + (size_t)T * 32768;          // 294912 fp32
  u16*  w3th   = (u16*)(w5t + 294912);            // 73728 u16 (16B aligned)
  u16*  w3tl   = w3th + 73728;
  u16*  w4th   = w3tl + 73728;                    // 147456 u16
  u16*  w4tl   = w4th + 147456;
  float* maskp = (float*)(w4tl + 147456);         // 1024
  float* accum = maskp + 1024;                    // 1
  float* outp  = (float*)d_out;

  k0_zero<<<1, 1, 0, stream>>>(accum);
  k_w5t<<<1152, 256, 0, stream>>>(w5, w5t);
  k_wprep<<<864, 256, 0, stream>>>(w3, w4, w3th, w3tl, w4th, w4tl);

  const int nchunks = 1024 / T;
  for (int c = 0; c < nchunks; ++c) {
    const int base = c * T;
    for (int s = 0; s < 2; ++s) {
      const float* src = s ? target : pred1;
      k1_conv1<<<T, 1024, 0, stream>>>(src, w1, b1, w2, b2, pool1, base);
      k2_mfma<<<T, 1024, 0, stream>>>(pool1, w3th, w3tl, w4th, w4tl, b3, b4,
                                      pool2 + (size_t)s * T * 8192);
    }
    k3_conv3_fft<<<T, 256, 0, stream>>>(pool2, w5t, b5, pool1, maskp, base, T);
  }
  k4_l1<<<1024, 256, 0, stream>>>((const float4*)pred2, (const float4*)target, maskp, accum);
  k5_final<<<1, 256, 0, stream>>>(accum, maskp, outp);
}

// Round 7
// 3845.002 us; speedup vs baseline: 2.3021x; 1.6824x over previous
//
#include <hip/hip_runtime.h>
#include <math.h>

// ---------------------------------------------------------------------------
// LphaLoss: blockwise VGG19(conv3_1) FFT-phase cosine mask + masked L1.
// R7: k2 wave decomposition transposed — wave = 16-co slice x 128 pixels.
//     Weight loads/wave 864 -> 108 (8x B-reuse); pooling shuffle-free.
//
// ws layout (floats), chunked over T tasks:
//   pool1 : [T][64][16][16]   = T*16384   (reused as phase buffer by k3)
//   pool2 : [2][T][128][8][8] = T*16384   (layout per block: [128 ch][64 s])
//   w5t   : [128*9][256]      = 294912    (transposed conv3 weights, fp32)
//   w3t   : [9][128co][64ci]  hi+lo bf16  (73728 u16 each)
//   w4t   : [9][128co][128ci] hi+lo bf16  (147456 u16 each)
//   mask  : [1024], accum : [1]
// ---------------------------------------------------------------------------

typedef float f8 __attribute__((ext_vector_type(8)));
typedef float f4v __attribute__((ext_vector_type(4)));
typedef short s8v __attribute__((ext_vector_type(8)));
typedef unsigned short u16;

__device__ __forceinline__ f8 sp8(float w) { return (f8){w, w, w, w, w, w, w, w}; }

__device__ __forceinline__ u16 bf16rn(float f) {
  union { float f; unsigned u; } x; x.f = f;
  return (u16)((x.u + 0x7FFFu + ((x.u >> 16) & 1u)) >> 16);
}
__device__ __forceinline__ float bfbits2f(u16 b) {
  union { float f; unsigned u; } x; x.u = ((unsigned)b) << 16;
  return x.f;
}

__device__ __forceinline__ float wave_reduce_sum(float v) {
#pragma unroll
  for (int off = 32; off > 0; off >>= 1) v += __shfl_down(v, off);
  return v;
}

__global__ void k0_zero(float* acc) { acc[0] = 0.f; }

// transpose w5 [256co][128ci][9] -> w5t [128ci*9][256co]
__global__ __launch_bounds__(256) void k_w5t(const float* __restrict__ w5,
                                             float* __restrict__ w5t) {
  const int e = blockIdx.x * 256 + threadIdx.x;   // grid 1152*256 = 294912
  const int co = e & 255, t = e >> 8;
  w5t[t * 256 + co] = w5[co * 1152 + t];
}

// split+transpose w3 [128co][64ci][9] -> [9][co][ci] hi/lo ; w4 likewise
__global__ __launch_bounds__(256) void k_wprep(const float* __restrict__ w3,
                                               const float* __restrict__ w4,
                                               u16* __restrict__ w3th, u16* __restrict__ w3tl,
                                               u16* __restrict__ w4th, u16* __restrict__ w4tl) {
  const int e = blockIdx.x * 256 + threadIdx.x;   // 864*256 = 221184
  float v; int o; u16* ph; u16* pl;
  if (e < 73728) {
    const int tap = e >> 13, r = e & 8191, co = r >> 6, ci = r & 63;
    v = w3[co * 576 + ci * 9 + tap]; o = e; ph = w3th; pl = w3tl;
  } else {
    const int e2 = e - 73728;
    const int tap = e2 >> 14, r = e2 & 16383, co = r >> 7, ci = r & 127;
    v = w4[co * 1152 + ci * 9 + tap]; o = e2; ph = w4th; pl = w4tl;
  }
  const u16 hb = bf16rn(v);
  const u16 lb = bf16rn(v - bfbits2f(hb));
  ph[o] = hb; pl[o] = lb;
}

// ---------------- K1: conv1_1+relu -> conv1_2+relu -> pool1 ----------------
// (unchanged — validated)
__global__ __launch_bounds__(1024) void k1_conv1(const float* __restrict__ src,
                                                 const float* __restrict__ w1,
                                                 const float* __restrict__ b1,
                                                 const float* __restrict__ w2,
                                                 const float* __restrict__ b2,
                                                 float* __restrict__ pool1,
                                                 int task_base) {
  const int btl = blockIdx.x;
  const int bt = btl + task_base;
  const int img = bt >> 6, by = (bt >> 3) & 7, bx = bt & 7;
  const int tid = threadIdx.x;

  __shared__ float lin[3 * 34 * 34];
  __shared__ float w1s[64 * 27];
  __shared__ float b1s[64], b2s[64];
  __shared__ float c11[64 * 10 * 34];

  for (int idx = tid; idx < 3 * 34 * 34; idx += 1024) {
    int c = idx / 1156;
    int rm = idx - c * 1156;
    int row = rm / 34;
    int xx = rm - row * 34 - 1;
    int yy = row - 1;
    float v = 0.f;
    if (yy >= 0 && yy < 32 && xx >= 0 && xx < 32) {
      float m = (c == 0) ? 0.485f : (c == 1) ? 0.456f : 0.406f;
      float sd = (c == 0) ? 0.229f : (c == 1) ? 0.224f : 0.225f;
      v = (src[((img * 3 + c) * 256 + (by * 32 + yy)) * 256 + (bx * 32 + xx)] - m) / sd;
    }
    lin[idx] = v;
  }
  for (int idx = tid; idx < 64 * 27; idx += 1024) w1s[idx] = w1[idx];
  if (tid < 64) b1s[tid] = b1[tid];
  else if (tid < 128) b2s[tid - 64] = b2[tid - 64];

  const int cogs = __builtin_amdgcn_readfirstlane(tid >> 6);  // wave id 0..15
  const int lane = tid & 63;
  const int col = lane & 31;
  const int rg = lane >> 5;

  __syncthreads();

  for (int q = 0; q < 4; ++q) {
    const int y0 = q * 8;
    if (q) __syncthreads();
    for (int e = tid; e < 64 * 10 * 34; e += 1024) {
      int ch = e / 340;
      int rm = e - ch * 340;
      int r = rm / 34;
      int xp = rm - r * 34;
      int y = y0 - 1 + r;
      int x = xp - 1;
      float v = 0.f;
      if (y >= 0 && y < 32 && x >= 0 && x < 32) {
        float a = b1s[ch];
        const float* wp = &w1s[ch * 27];
#pragma unroll
        for (int ci = 0; ci < 3; ++ci) {
          const float* lp = &lin[ci * 1156 + y * 34 + x];
#pragma unroll
          for (int ky = 0; ky < 3; ++ky)
#pragma unroll
            for (int kx = 0; kx < 3; ++kx)
              a = fmaf(lp[ky * 34 + kx], wp[ci * 9 + ky * 3 + kx], a);
        }
        v = fmaxf(a, 0.f);
      }
      c11[e] = v;
    }
    __syncthreads();

    float acc[4][4];
#pragma unroll
    for (int a = 0; a < 4; ++a)
#pragma unroll
      for (int rr = 0; rr < 4; ++rr) acc[a][rr] = 0.f;

    const float* w2g = w2 + cogs * 4 * 576;
    for (int ci = 0; ci < 64; ++ci) {
      const float* c1b = &c11[ci * 340];
#pragma unroll
      for (int ky = 0; ky < 3; ++ky) {
#pragma unroll
        for (int kx = 0; kx < 3; ++kx) {
          const float* w2c = w2g + ci * 9 + ky * 3 + kx;
          float wv[4];
#pragma unroll
          for (int a = 0; a < 4; ++a) wv[a] = w2c[a * 576];
          const float in0 = c1b[(rg + 0 + ky) * 34 + col + kx];
          const float in1 = c1b[(rg + 2 + ky) * 34 + col + kx];
          const float in2 = c1b[(rg + 4 + ky) * 34 + col + kx];
          const float in3 = c1b[(rg + 6 + ky) * 34 + col + kx];
#pragma unroll
          for (int a = 0; a < 4; ++a) {
            acc[a][0] = fmaf(in0, wv[a], acc[a][0]);
            acc[a][1] = fmaf(in1, wv[a], acc[a][1]);
            acc[a][2] = fmaf(in2, wv[a], acc[a][2]);
            acc[a][3] = fmaf(in3, wv[a], acc[a][3]);
          }
        }
      }
    }
#pragma unroll
    for (int a = 0; a < 4; ++a) {
      const int co = cogs * 4 + a;
      const float bb = b2s[co];
#pragma unroll
      for (int rr = 0; rr < 4; ++rr) {
        float v = fmaxf(acc[a][rr] + bb, 0.f);
        v = fmaxf(v, __shfl_xor(v, 1));
        v = fmaxf(v, __shfl_xor(v, 32));
        if (rg == 0 && !(col & 1))
          pool1[((btl * 64 + co) * 16 + q * 4 + rr) * 16 + (col >> 1)] = v;
      }
    }
  }
}

// ---------------- K2: MFMA bf16x3, co-sliced waves ----------------
// 1024 thr = 16 waves = 8 co-groups (16 co) x 2 m-halves (8 rows of 16 px).
// m-tile = one image row (16 px). A: lane&15 = x, grp = k-granule.
// B: lane&15 = co-in-group, grp = k-granule. C: col=lane&15 -> co,
// grp*4+r -> x. Vertical pool pairs live in acc[mt],acc[mt+1] of SAME wave.
// Zero LDS row at pix=256 absorbs halo (no cndmask).
__global__ __launch_bounds__(1024) void k2_mfma(const float* __restrict__ pool1,
                                                const u16* __restrict__ w3th,
                                                const u16* __restrict__ w3tl,
                                                const u16* __restrict__ w4th,
                                                const u16* __restrict__ w4tl,
                                                const float* __restrict__ b3,
                                                const float* __restrict__ b4,
                                                float* __restrict__ pool2) {
  const int bt = blockIdx.x;
  const int tid = threadIdx.x;
  __shared__ u16 umem[66048];               // 129 KB union
  __shared__ float b3s[128], b4s[128];
  u16* img1h = umem;                        // [257 pix][64 ci] (row 256 = zeros)
  u16* img1l = umem + 16448;
  u16* img2h = umem;                        // [257 pix][128 ci]
  u16* img2l = umem + 32896;
  float* pbuf = (float*)umem;               // [128 ch][66] padded

  // ---- phase 0: stage pool1 -> img1 (hi/lo split, swizzled) ----
  for (int e = tid; e < 16384; e += 1024) {
    const int ci = e >> 8, pix = e & 255;
    const float v = pool1[bt * 16384 + e];
    const u16 hb = bf16rn(v);
    const u16 lb = bf16rn(v - bfbits2f(hb));
    const int idx = pix * 64 + ((((ci >> 3) ^ pix) & 7) << 3) + (ci & 7);
    img1h[idx] = hb; img1l[idx] = lb;
  }
  if (tid < 64) { img1h[16384 + tid] = 0; img1l[16384 + tid] = 0; }
  if (tid < 128) b3s[tid] = b3[tid];
  else if (tid < 256) b4s[tid - 128] = b4[tid - 128];
  __syncthreads();

  const int w = tid >> 6, lane = tid & 63;
  const int wco = w & 7, wm = w >> 3;
  const int cobase = wco << 4;
  const int col = lane & 15, grp = lane >> 4;

  f4v acc[8];
#pragma unroll
  for (int m = 0; m < 8; ++m) acc[m] = (f4v){0.f, 0.f, 0.f, 0.f};

  // ---- phase 1: conv2_1 MFMA (K = 9 taps x 64 ci) ----
  for (int tap = 0; tap < 9; ++tap) {
    const int dy = (tap >= 6) ? 2 : (tap >= 3) ? 1 : 0;
    const int dx = tap - dy * 3;
    const int xin = col + dx - 1;
    const bool xok = ((unsigned)xin < 16u);
#pragma unroll
    for (int ks = 0; ks < 2; ++ks) {
      const int wb = (tap * 128 + cobase + col) * 64 + (ks << 5) + (grp << 3);
      const s8v bh = *(const s8v*)(w3th + wb);
      const s8v bl = *(const s8v*)(w3tl + wb);
#pragma unroll
      for (int mt = 0; mt < 8; ++mt) {
        const int yin = wm * 8 + mt + dy - 1;
        const int pix = (xok && ((unsigned)yin < 16u)) ? yin * 16 + xin : 256;
        const int gi = pix * 64 + (((((ks << 2) + grp) ^ xin) & 7) << 3);
        const s8v ah = *(const s8v*)(img1h + gi);
        const s8v al = *(const s8v*)(img1l + gi);
        acc[mt] = __builtin_amdgcn_mfma_f32_16x16x32_bf16(ah, bh, acc[mt], 0, 0, 0);
        acc[mt] = __builtin_amdgcn_mfma_f32_16x16x32_bf16(ah, bl, acc[mt], 0, 0, 0);
        acc[mt] = __builtin_amdgcn_mfma_f32_16x16x32_bf16(al, bh, acc[mt], 0, 0, 0);
      }
    }
  }
  __syncthreads();   // all img1 reads complete (img2 aliases img1)

  // ---- phase 2: bias+relu, split, write img2 ----
  if (tid < 128) { img2h[32768 + tid] = 0; img2l[32768 + tid] = 0; }
  {
    const float bb = b3s[cobase + col];
    const int co = cobase + col;
#pragma unroll
    for (int mt = 0; mt < 8; ++mt) {
      const int y = wm * 8 + mt;
#pragma unroll
      for (int r = 0; r < 4; ++r) {
        const int x = (grp << 2) + r;
        const int pix = y * 16 + x;
        float v = fmaxf(acc[mt][r] + bb, 0.f);
        const u16 hb = bf16rn(v);
        const u16 lb = bf16rn(v - bfbits2f(hb));
        const int idx = pix * 128 + ((((co >> 3) ^ x) & 15) << 3) + (co & 7);
        img2h[idx] = hb; img2l[idx] = lb;
      }
    }
  }
  __syncthreads();

  // ---- phase 3: conv2_2 MFMA (K = 9 taps x 128 ci) ----
#pragma unroll
  for (int m = 0; m < 8; ++m) acc[m] = (f4v){0.f, 0.f, 0.f, 0.f};
  for (int tap = 0; tap < 9; ++tap) {
    const int dy = (tap >= 6) ? 2 : (tap >= 3) ? 1 : 0;
    const int dx = tap - dy * 3;
    const int xin = col + dx - 1;
    const bool xok = ((unsigned)xin < 16u);
#pragma unroll
    for (int ks = 0; ks < 4; ++ks) {
      const int wb = (tap * 128 + cobase + col) * 128 + (ks << 5) + (grp << 3);
      const s8v bh = *(const s8v*)(w4th + wb);
      const s8v bl = *(const s8v*)(w4tl + wb);
#pragma unroll
      for (int mt = 0; mt < 8; ++mt) {
        const int yin = wm * 8 + mt + dy - 1;
        const int pix = (xok && ((unsigned)yin < 16u)) ? yin * 16 + xin : 256;
        const int gi = pix * 128 + (((((ks << 2) + grp) ^ xin) & 15) << 3);
        const s8v ah = *(const s8v*)(img2h + gi);
        const s8v al = *(const s8v*)(img2l + gi);
        acc[mt] = __builtin_amdgcn_mfma_f32_16x16x32_bf16(ah, bh, acc[mt], 0, 0, 0);
        acc[mt] = __builtin_amdgcn_mfma_f32_16x16x32_bf16(ah, bl, acc[mt], 0, 0, 0);
        acc[mt] = __builtin_amdgcn_mfma_f32_16x16x32_bf16(al, bh, acc[mt], 0, 0, 0);
      }
    }
  }
  __syncthreads();   // img2 reads complete (pbuf aliases img2)

  // ---- phase 4: bias+relu + shuffle-free 2x2 pool -> pbuf ----
  {
    const int co = cobase + col;
    const float bb = b4s[co];
#pragma unroll
    for (int mp = 0; mp < 4; ++mp) {
      const float v0 = fmaxf(acc[2 * mp][0] + bb, 0.f);
      const float v1 = fmaxf(acc[2 * mp][1] + bb, 0.f);
      const float v2 = fmaxf(acc[2 * mp][2] + bb, 0.f);
      const float v3 = fmaxf(acc[2 * mp][3] + bb, 0.f);
      const float u0 = fmaxf(acc[2 * mp + 1][0] + bb, 0.f);
      const float u1 = fmaxf(acc[2 * mp + 1][1] + bb, 0.f);
      const float u2 = fmaxf(acc[2 * mp + 1][2] + bb, 0.f);
      const float u3 = fmaxf(acc[2 * mp + 1][3] + bb, 0.f);
      const float p0 = fmaxf(fmaxf(v0, v1), fmaxf(u0, u1));
      const float p1 = fmaxf(fmaxf(v2, v3), fmaxf(u2, u3));
      const int s = (wm * 4 + mp) * 8 + grp * 2;
      pbuf[co * 66 + s] = p0;
      pbuf[co * 66 + s + 1] = p1;
    }
  }
  __syncthreads();

  // ---- phase 5: coalesced pbuf -> pool2 ([128 ch][64 s] per block) ----
  for (int e = tid; e < 8192; e += 1024)
    pool2[bt * 8192 + e] = pbuf[(e >> 6) * 66 + (e & 63)];
}

// -------- K3: conv3_1 (both streams) + FFT2 phase + cosine sim -> mask -----
#define C707 0.70710678118654752f

#define FFT8(R0,R1,R2,R3,R4,R5,R6,R7,I0,I1,I2,I3,I4,I5,I6,I7) {              \
  float er0=R0+R4, er1=R0-R4, ei0=I0+I4, ei1=I0-I4;                          \
  float er2=R2+R6, er3=R2-R6, ei2=I2+I6, ei3=I2-I6;                          \
  float E0r=er0+er2, E0i=ei0+ei2, E2r=er0-er2, E2i=ei0-ei2;                  \
  float E1r=er1+ei3, E1i=ei1-er3, E3r=er1-ei3, E3i=ei1+er3;                  \
  float or0=R1+R5, or1=R1-R5, oi0=I1+I5, oi1=I1-I5;                          \
  float or2=R3+R7, or3=R3-R7, oi2=I3+I7, oi3=I3-I7;                          \
  float O0r=or0+or2, O0i=oi0+oi2, O2r=or0-or2, O2i=oi0-oi2;                  \
  float O1r=or1+oi3, O1i=oi1-or3, O3r=or1-oi3, O3i=oi1+or3;                  \
  float T1r=C707*(O1r+O1i), T1i=C707*(O1i-O1r);                              \
  float T2r=O2i, T2i=-O2r;                                                   \
  float T3r=C707*(O3i-O3r), T3i=-C707*(O3r+O3i);                             \
  R0=E0r+O0r; I0=E0i+O0i; R4=E0r-O0r; I4=E0i-O0i;                            \
  R1=E1r+T1r; I1=E1i+T1i; R5=E1r-T1r; I5=E1i-T1i;                            \
  R2=E2r+T2r; I2=E2i+T2i; R6=E2r-T2r; I6=E2i-T2i;                            \
  R3=E3r+T3r; I3=E3i+T3i; R7=E3r-T3r; I7=E3i-T3i;                            \
}

#define CONVROW(IR, AP, AC, AN) {                                            \
  const float4 lo = *(const float4*)(lc + (IR) * 8);                         \
  const float4 hi = *(const float4*)(lc + (IR) * 8 + 4);                     \
  f8 vm = {0.f, lo.x, lo.y, lo.z, lo.w, hi.x, hi.y, hi.z};                   \
  f8 vc = {lo.x, lo.y, lo.z, lo.w, hi.x, hi.y, hi.z, hi.w};                  \
  f8 vp = {lo.y, lo.z, lo.w, hi.x, hi.y, hi.z, hi.w, 0.f};                   \
  AN = __builtin_elementwise_fma(vm, sp8(wv0), AN);                          \
  AN = __builtin_elementwise_fma(vc, sp8(wv1), AN);                          \
  AN = __builtin_elementwise_fma(vp, sp8(wv2), AN);                          \
  AC = __builtin_elementwise_fma(vm, sp8(wv3), AC);                          \
  AC = __builtin_elementwise_fma(vc, sp8(wv4), AC);                          \
  AC = __builtin_elementwise_fma(vp, sp8(wv5), AC);                          \
  AP = __builtin_elementwise_fma(vm, sp8(wv6), AP);                          \
  AP = __builtin_elementwise_fma(vc, sp8(wv7), AP);                          \
  AP = __builtin_elementwise_fma(vp, sp8(wv8), AP);                          \
}

#define ROWFFT(Y, AV) {                                                      \
  float r0=AV[0],r1=AV[1],r2=AV[2],r3=AV[3],r4=AV[4],r5=AV[5],r6=AV[6],r7=AV[7]; \
  float i0=0.f,i1=0.f,i2=0.f,i3=0.f,i4=0.f,i5=0.f,i6=0.f,i7=0.f;             \
  FFT8(r0,r1,r2,r3,r4,r5,r6,r7,i0,i1,i2,i3,i4,i5,i6,i7);                     \
  cr0[Y]=r0; ci0[Y]=i0; cr1[Y]=r1; ci1[Y]=i1; cr2[Y]=r2; ci2[Y]=i2;          \
  cr3[Y]=r3; ci3[Y]=i3; cr4[Y]=r4; ci4[Y]=i4; cr5[Y]=r5; ci5[Y]=i5;          \
  cr6[Y]=r6; ci6[Y]=i6; cr7[Y]=r7; ci7[Y]=i7;                                \
}

#define PH(RE, IM, PIDX) {                                                   \
  const float ph = atan2f(IM, RE);                                           \
  if (first) { phw[(PIDX) * 256] = ph; n1 = fmaf(ph, ph, n1); }              \
  else { const float qv = phw[(PIDX) * 256];                                 \
         dt = fmaf(ph, qv, dt); n2 = fmaf(ph, ph, n2); }                     \
}

#define COLPH(K) {                                                           \
  float r0=cr##K[0],r1=cr##K[1],r2=cr##K[2],r3=cr##K[3],r4=cr##K[4],r5=cr##K[5],r6=cr##K[6],r7=cr##K[7]; \
  float i0=ci##K[0],i1=ci##K[1],i2=ci##K[2],i3=ci##K[3],i4=ci##K[4],i5=ci##K[5],i6=ci##K[6],i7=ci##K[7]; \
  FFT8(r0,r1,r2,r3,r4,r5,r6,r7,i0,i1,i2,i3,i4,i5,i6,i7);                     \
  PH(r0,i0,0*8+K) PH(r1,i1,1*8+K) PH(r2,i2,2*8+K) PH(r3,i3,3*8+K)            \
  PH(r4,i4,4*8+K) PH(r5,i5,5*8+K) PH(r6,i6,6*8+K) PH(r7,i7,7*8+K)            \
}

__global__ __launch_bounds__(256, 2) void k3_conv3_fft(const float* __restrict__ pool2,
                                                       const float* __restrict__ w5t,
                                                       const float* __restrict__ b5,
                                                       float* __restrict__ phase_ws,
                                                       float* __restrict__ maskp,
                                                       int task_base, int T) {
  const int b = blockIdx.x;
  const int tid = threadIdx.x;               // = output channel co
  __shared__ float4 lin4[2048];              // 32 KB: [128ci][8][8] fp32
  __shared__ float rbuf[12];
  float* lin = (float*)lin4;

  const float bias = b5[tid];
  float n1 = 0.f, n2 = 0.f, dt = 0.f;
  float* phw = phase_ws + (size_t)b * 16384 + tid;   // [px][co] px-major

  for (int s = 0; s < 2; ++s) {
    const bool first = (s == 0);
    __syncthreads();
    const float4* src4 = (const float4*)pool2 + (size_t)(s * T + b) * 2048;
    for (int idx = tid; idx < 2048; idx += 256) lin4[idx] = src4[idx];
    __syncthreads();

    f8 a0 = sp8(bias), a1 = sp8(bias), a2 = sp8(bias), a3 = sp8(bias);
    f8 a4 = sp8(bias), a5 = sp8(bias), a6 = sp8(bias), a7 = sp8(bias);
    f8 adump = sp8(0.f);

    for (int ci = 0; ci < 128; ++ci) {
      const float* wvp = w5t + ci * 9 * 256 + tid;
      const float wv0 = wvp[0], wv1 = wvp[256], wv2 = wvp[512];
      const float wv3 = wvp[768], wv4 = wvp[1024], wv5 = wvp[1280];
      const float wv6 = wvp[1536], wv7 = wvp[1792], wv8 = wvp[2048];
      const float* lc = lin + ci * 64;
      CONVROW(0, adump, a0, a1)
      CONVROW(1, a0, a1, a2)
      CONVROW(2, a1, a2, a3)
      CONVROW(3, a2, a3, a4)
      CONVROW(4, a3, a4, a5)
      CONVROW(5, a4, a5, a6)
      CONVROW(6, a5, a6, a7)
      CONVROW(7, a6, a7, adump)
    }

    f8 cr0, cr1, cr2, cr3, cr4, cr5, cr6, cr7;
    f8 ci0, ci1, ci2, ci3, ci4, ci5, ci6, ci7;
    ROWFFT(0, a0) ROWFFT(1, a1) ROWFFT(2, a2) ROWFFT(3, a3)
    ROWFFT(4, a4) ROWFFT(5, a5) ROWFFT(6, a6) ROWFFT(7, a7)
    COLPH(0) COLPH(1) COLPH(2) COLPH(3) COLPH(4) COLPH(5) COLPH(6) COLPH(7)
  }

  dt = wave_reduce_sum(dt);
  n1 = wave_reduce_sum(n1);
  n2 = wave_reduce_sum(n2);
  if ((tid & 63) == 0) {
    rbuf[(tid >> 6) * 3 + 0] = dt;
    rbuf[(tid >> 6) * 3 + 1] = n1;
    rbuf[(tid >> 6) * 3 + 2] = n2;
  }
  __syncthreads();
  if (tid == 0) {
    float D = 0.f, A = 0.f, B2 = 0.f;
#pragma unroll
    for (int w = 0; w < 4; ++w) { D += rbuf[w * 3]; A += rbuf[w * 3 + 1]; B2 += rbuf[w * 3 + 2]; }
    const float den = fmaxf(sqrtf(A) * sqrtf(B2), 1e-8f);
    maskp[task_base + b] = ((D / den) >= 0.2f) ? 1.f : 0.f;
  }
}

// ---------------- K4: masked L1 partial reduce ----------------
__global__ __launch_bounds__(256) void k4_l1(const float4* __restrict__ pred2,
                                             const float4* __restrict__ target,
                                             const float* __restrict__ maskp,
                                             float* __restrict__ accum) {
  const int gid = blockIdx.x * 256 + threadIdx.x;
  float part = 0.f;
  for (int e = gid; e < 786432; e += 262144) {
    const int flat = e << 2;
    const int i = flat / 196608;
    const int rem = flat - i * 196608;
    const int pix = rem & 65535;
    const int y = pix >> 8, x = pix & 255;
    const int b = (i << 6) + ((y >> 5) << 3) + (x >> 5);
    if (maskp[b] != 0.f) {
      const float4 p = pred2[e];
      const float4 t = target[e];
      part += fabsf(p.x - t.x) + fabsf(p.y - t.y) + fabsf(p.z - t.z) + fabsf(p.w - t.w);
    }
  }
  part = wave_reduce_sum(part);
  __shared__ float rb[4];
  if ((threadIdx.x & 63) == 0) rb[threadIdx.x >> 6] = part;
  __syncthreads();
  if (threadIdx.x == 0) atomicAdd(accum, rb[0] + rb[1] + rb[2] + rb[3]);
}

// ---------------- K5: finalize ----------------
__global__ __launch_bounds__(256) void k5_final(const float* __restrict__ accum,
                                                const float* __restrict__ maskp,
                                                float* __restrict__ out) {
  float c = 0.f;
  for (int i = threadIdx.x; i < 1024; i += 256) c += maskp[i];
  c = wave_reduce_sum(c);
  __shared__ float rb[4];
  if ((threadIdx.x & 63) == 0) rb[threadIdx.x >> 6] = c;
  __syncthreads();
  if (threadIdx.x == 0) {
    const float cnt = rb[0] + rb[1] + rb[2] + rb[3];
    out[0] = accum[0] / (cnt * 1024.f + 1e-6f);
  }
}

// ---------------------------------------------------------------------------
extern "C" void kernel_launch(void* const* d_in, const int* in_sizes, int n_in,
                              void* d_out, int out_size, void* d_ws, size_t ws_size,
                              hipStream_t stream) {
  (void)in_sizes; (void)n_in; (void)out_size;
  const float* pred1  = (const float*)d_in[0];
  const float* pred2  = (const float*)d_in[1];
  const float* target = (const float*)d_in[2];
  const float* w1 = (const float*)d_in[3];  const float* b1 = (const float*)d_in[4];
  const float* w2 = (const float*)d_in[5];  const float* b2 = (const float*)d_in[6];
  const float* w3 = (const float*)d_in[7];  const float* b3 = (const float*)d_in[8];
  const float* w4 = (const float*)d_in[9];  const float* b4 = (const float*)d_in[10];
  const float* w5 = (const float*)d_in[11]; const float* b5 = (const float*)d_in[12];

  // footprint(T) = (T*32768 + 294912 + 221184 + 2048) floats
  int T = 8;
  for (int cand = 1024; cand >= 8; cand >>= 1) {
    const size_t need = ((size_t)cand * 32768 + 294912 + 221184 + 2048) * sizeof(float);
    if (need <= ws_size) { T = cand; break; }
  }

  float* ws    = (float*)d_ws;
  float* pool1 = ws;                              // T*16384 (also k3 phase buf)
  float* pool2 = ws + (size_t)T * 16384;          // T*16384
  float* w5t   = ws + (size_t)T * 32768;          // 294912 fp32
  u16*  w3th   = (u16*)(w5t + 294912);            // 73728 u16 (16B aligned)
  u16*  w3tl   = w3th + 73728;
  u16*  w4th   = w3tl + 73728;                    // 147456 u16
  u16*  w4tl   = w4th + 147456;
  float* maskp = (float*)(w4tl + 147456);         // 1024
  float* accum = maskp + 1024;                    // 1
  float* outp  = (float*)d_out;

  k0_zero<<<1, 1, 0, stream>>>(accum);
  k_w5t<<<1152, 256, 0, stream>>>(w5, w5t);
  k_wprep<<<864, 256, 0, stream>>>(w3, w4, w3th, w3tl, w4th, w4tl);

  const int nchunks = 1024 / T;
  for (int c = 0; c < nchunks; ++c) {
    const int base = c * T;
    for (int s = 0; s < 2; ++s) {
      const float* src = s ? target : pred1;
      k1_conv1<<<T, 1024, 0, stream>>>(src, w1, b1, w2, b2, pool1, base);
      k2_mfma<<<T, 1024, 0, stream>>>(pool1, w3th, w3tl, w4th, w4tl, b3, b4,
                                      pool2 + (size_t)s * T * 8192);
    }
    k3_conv3_fft<<<T, 256, 0, stream>>>(pool2, w5t, b5, pool1, maskp, base, T);
  }
  k4_l1<<<1024, 256, 0, stream>>>((const float4*)pred2, (const float4*)target, maskp, accum);
  k5_final<<<1, 256, 0, stream>>>(accum, maskp, outp);
}